// Round 1
// 1135.384 us; speedup vs baseline: 1.0079x; 1.0079x over previous
//
#include <hip/hip_runtime.h>

// MLA shapes (fixed)
#define B_ 4
#define S_ 1024
#define H_ 4096
#define NH_ 32
#define QHD_ 192
#define EPS_ 1e-6f

typedef __bf16 bf16x8 __attribute__((ext_vector_type(8)));
typedef float floatx4 __attribute__((ext_vector_type(4)));

__device__ __forceinline__ unsigned short f2bf(float f) {
  unsigned int u = __builtin_bit_cast(unsigned int, f);
  u += 0x7fffu + ((u >> 16) & 1u);   // round-to-nearest-even (finite data only)
  return (unsigned short)(u >> 16);
}
__device__ __forceinline__ float bf2f(unsigned short s) {
  return __builtin_bit_cast(float, ((unsigned int)s) << 16);
}

// async global->LDS, 16B per lane; LDS dest = wave-uniform base + lane*16 (m104)
__device__ __forceinline__ void gload16(const unsigned short* g, unsigned short* l) {
  __builtin_amdgcn_global_load_lds(
      (const __attribute__((address_space(1))) void*)g,
      (__attribute__((address_space(3))) void*)l, 16, 0, 0);
}

// ---------------------------------------------------------------------------
// fp32 -> bf16 convert (hs), 8 elems/thread
// ---------------------------------------------------------------------------
__global__ __launch_bounds__(256) void convert_kernel(
    const float* __restrict__ x, unsigned short* __restrict__ y)
{
  const int i = (blockIdx.x * 256 + threadIdx.x) * 8;
  const float4 a = *(const float4*)(x + i);
  const float4 b = *(const float4*)(x + i + 4);
  ushort4 u, v;
  u.x = f2bf(a.x); u.y = f2bf(a.y); u.z = f2bf(a.z); u.w = f2bf(a.w);
  v.x = f2bf(b.x); v.y = f2bf(b.y); v.z = f2bf(b.z); v.w = f2bf(b.w);
  *(ushort4*)(y + i) = u;
  *(ushort4*)(y + i + 4) = v;
}

// ---------------------------------------------------------------------------
// W (KxN fp32 row-major) -> Wt (NxK bf16 row-major). 32x32 LDS tiles.
// ---------------------------------------------------------------------------
__global__ __launch_bounds__(256) void transpose_kernel(
    const float* __restrict__ W, unsigned short* __restrict__ Wt,
    const int K, const int N)
{
  __shared__ float tile[32][33];
  const int tx = threadIdx.x & 31, ty = threadIdx.x >> 5;
  const int nb = blockIdx.x << 5, kb = blockIdx.y << 5;
#pragma unroll
  for (int j = 0; j < 4; ++j)
    tile[ty + j * 8][tx] = W[(size_t)(kb + ty + j * 8) * N + nb + tx];
  __syncthreads();
#pragma unroll
  for (int j = 0; j < 4; ++j)
    Wt[(size_t)(nb + ty + j * 8) * K + kb + tx] = f2bf(tile[tx][ty + j * 8]);
}

// ---------------------------------------------------------------------------
// m97-class GEMM: C(MxN) = A(MxK) @ Bt(NxK)^T, both bf16, staged via
// global_load_lds width=16 into unpadded LDS [128][32]. 128x128 tile, BK=32,
// 4 waves (2x2 of 64x64), mfma_f32_16x16x32_bf16.
// OMODE: 0 = fp32 row-major, 1 = bf16 row-major, 2 = bf16 (B,NH,S,256) kv.
// M%128==0, K%32==0; Bt rows padded to 128-mult (pad contents finite poison).
// ---------------------------------------------------------------------------
template<int OMODE>
__global__ __launch_bounds__(256, 2) void gemm_bt(
    const unsigned short* __restrict__ A, const unsigned short* __restrict__ Bt,
    void* __restrict__ Cv, const int N, const int K,
    const int lda, const int ldb, const int ldc)
{
  __shared__ unsigned short As[128 * 32];
  __shared__ unsigned short Bs[128 * 32];

  const int t = threadIdx.x;
  const int m0 = blockIdx.x * 128, n0 = blockIdx.y * 128;
  const int w = t >> 6, lane = t & 63;
  const int wm = (w >> 1) << 6, wn = (w & 1) << 6;
  const int lm = lane & 15, lq = lane >> 4;

  const floatx4 vzero = {0.f, 0.f, 0.f, 0.f};
  floatx4 acc[4][4];
#pragma unroll
  for (int i = 0; i < 4; ++i)
#pragma unroll
    for (int j = 0; j < 4; ++j) acc[i][j] = vzero;

  // staging: wave w does calls i=0,1; call covers 16 rows x 32 cols (1 KB).
  // lane -> row (w*32 + i*16 + lane/4), chunk kc = lane&3 (8 shorts).
  const int srow = (w << 5) + (lane >> 2);
  const int skc = (lane & 3) << 3;
  const unsigned short* gA = A + (size_t)(m0 + srow) * lda + skc;
  const unsigned short* gB = Bt + (size_t)(n0 + srow) * ldb + skc;
  unsigned short* lA0 = &As[(w << 1) * 512];
  unsigned short* lA1 = &As[((w << 1) + 1) * 512];
  unsigned short* lB0 = &Bs[(w << 1) * 512];
  unsigned short* lB1 = &Bs[((w << 1) + 1) * 512];

  const int nk = K >> 5;
  for (int kb = 0; kb < nk; ++kb) {
    const int k0 = kb << 5;
    __syncthreads();
    gload16(gA + k0, lA0);
    gload16(gA + (size_t)16 * lda + k0, lA1);
    gload16(gB + k0, lB0);
    gload16(gB + (size_t)16 * ldb + k0, lB1);
    __syncthreads();

    bf16x8 af[4], bfr[4];
#pragma unroll
    for (int mi = 0; mi < 4; ++mi)
      af[mi] = *(const bf16x8*)&As[(wm + mi * 16 + lm) * 32 + (lq << 3)];
#pragma unroll
    for (int ni = 0; ni < 4; ++ni)
      bfr[ni] = *(const bf16x8*)&Bs[(wn + ni * 16 + lm) * 32 + (lq << 3)];
#pragma unroll
    for (int mi = 0; mi < 4; ++mi)
#pragma unroll
      for (int ni = 0; ni < 4; ++ni)
        acc[mi][ni] = __builtin_amdgcn_mfma_f32_16x16x32_bf16(af[mi], bfr[ni], acc[mi][ni], 0, 0, 0);
  }

#pragma unroll
  for (int mi = 0; mi < 4; ++mi) {
    const int row = m0 + wm + mi * 16 + (lq << 2);
#pragma unroll
    for (int ni = 0; ni < 4; ++ni) {
      const int col = n0 + wn + ni * 16 + lm;
      if (col < N) {
#pragma unroll
        for (int r = 0; r < 4; ++r) {
          if constexpr (OMODE == 0)
            ((float*)Cv)[(size_t)(row + r) * ldc + col] = acc[mi][ni][r];
          else if constexpr (OMODE == 1)
            ((unsigned short*)Cv)[(size_t)(row + r) * ldc + col] = f2bf(acc[mi][ni][r]);
          else {
            const int rr2 = row + r;  // (B,NH,S,256): h=col>>8, d=col&255
            ((unsigned short*)Cv)[(((size_t)(rr2 >> 10) * NH_ + (col >> 8)) * S_ + (rr2 & 1023)) * 256 + (col & 255)] = f2bf(acc[mi][ni][r]);
          }
        }
      }
    }
  }
}

// ---------------------------------------------------------------------------
// LayerNorm: x fp32 rows (len L, stride xstride) -> y bf16 (stride ystride).
// ---------------------------------------------------------------------------
__global__ __launch_bounds__(256) void ln_kernel(
    const float* __restrict__ x, const float* __restrict__ g,
    const float* __restrict__ bias, unsigned short* __restrict__ y,
    const int L, const int xstride, const int ystride)
{
  __shared__ float sh[4];
  const int t = threadIdx.x;
  const float* xr = x + (size_t)blockIdx.x * xstride;
  unsigned short* yr = y + (size_t)blockIdx.x * ystride;
  const int n = L >> 8;
  float vals[6];
  float s = 0.f;
  for (int i = 0; i < n; ++i) { vals[i] = xr[t + (i << 8)]; s += vals[i]; }
#pragma unroll
  for (int off = 32; off; off >>= 1) s += __shfl_down(s, off);
  if ((t & 63) == 0) sh[t >> 6] = s;
  __syncthreads();
  const float mean = (sh[0] + sh[1] + sh[2] + sh[3]) / (float)L;
  float vs = 0.f;
  for (int i = 0; i < n; ++i) { const float d = vals[i] - mean; vs += d * d; }
#pragma unroll
  for (int off = 32; off; off >>= 1) vs += __shfl_down(vs, off);
  __syncthreads();
  if ((t & 63) == 0) sh[t >> 6] = vs;
  __syncthreads();
  const float inv = rsqrtf((sh[0] + sh[1] + sh[2] + sh[3]) / (float)L + EPS_);
  for (int i = 0; i < n; ++i) {
    const int c = t + (i << 8);
    yr[c] = f2bf((vals[i] - mean) * inv * g[c] + bias[c]);
  }
}

// ---------------------------------------------------------------------------
// RoPE on q_pe (cols 128..191 of each 192-wide head), in place on bf16 q.
// ---------------------------------------------------------------------------
__global__ __launch_bounds__(256) void rope_q_kernel(
    unsigned short* __restrict__ q, const float* __restrict__ cosp,
    const float* __restrict__ sinp, const int* __restrict__ pos)
{
  const int i = blockIdx.x * 256 + threadIdx.x;  // B*S*NH*32
  const int p = i & 31;
  const int h = (i >> 5) & 31;
  const int bs = i >> 10;
  const int pid = pos[bs];
  const size_t base = ((size_t)bs * NH_ + h) * QHD_ + 128;
  const float x1 = bf2f(q[base + p]);
  const float x2 = bf2f(q[base + p + 32]);
  const float* cr = cosp + (size_t)pid * 64;
  const float* sr = sinp + (size_t)pid * 64;
  q[base + p]      = f2bf(x1 * cr[p] - x2 * sr[p]);
  q[base + p + 32] = f2bf(x2 * cr[p + 32] + x1 * sr[p + 32]);
}

// RoPE on k_pe: ckv cols 512..575 (fp32) -> kpe bf16 (B,S,64)
__global__ __launch_bounds__(256) void rope_k_kernel(
    const float* __restrict__ ckv, const float* __restrict__ cosp,
    const float* __restrict__ sinp, const int* __restrict__ pos,
    unsigned short* __restrict__ kpe)
{
  const int i = blockIdx.x * 256 + threadIdx.x;  // B*S*32
  const int p = i & 31;
  const int bs = i >> 5;
  const int pid = pos[bs];
  const float* row = ckv + (size_t)bs * 576 + 512;
  const float x1 = row[p], x2 = row[p + 32];
  const float* cr = cosp + (size_t)pid * 64;
  const float* sr = sinp + (size_t)pid * 64;
  kpe[(size_t)bs * 64 + p]      = f2bf(x1 * cr[p] - x2 * sr[p]);
  kpe[(size_t)bs * 64 + p + 32] = f2bf(x2 * cr[p + 32] + x1 * sr[p + 32]);
}

// ---------------------------------------------------------------------------
// MFMA flash attention. Block = 4 waves = (b,h,64 q).
// Round-3 changes:
//  (a) Vt XOR-swizzle: dword col ^= ((row>>3)&7)<<2. Kills the 16-way bank
//      conflict on the V-transpose u32 writes (288 dwords/8rows === 0 mod 32
//      meant all 16 cg-lanes of a group hit one bank). Reads stay b128-legal
//      (XOR touches dword bits [4:2] only).
//  (b) T14 async-STAGE split: next tile's K/V/kpe global loads are issued
//      into 10 uint4 regs right after the compute barrier, overlapping the
//      whole QK/softmax/PV phase; only regs->LDS sits between barriers.
// ---------------------------------------------------------------------------
__global__ __launch_bounds__(256) void attn_kernel(
    const unsigned short* __restrict__ qb, const unsigned short* __restrict__ kvb,
    const unsigned short* __restrict__ kpe, unsigned short* __restrict__ o)
{
  __shared__ unsigned short Ks[64 * 200];      // [k][d 0..191], stride 200
  __shared__ unsigned short Vt[128 * 72];      // [vd][k], stride 72, swizzled cols
  __shared__ unsigned short Ps[4 * 16 * 72];   // per-wave [m][k], stride 72

  const int t = threadIdx.x;
  const int qt = (int)gridDim.x - 1 - (int)blockIdx.x;  // longest first
  const int h = blockIdx.y, b = blockIdx.z;
  const int w = t >> 6, lane = t & 63;
  const int lm = lane & 15, lq = lane >> 4;
  const float SCALE = 0.07216878364870322f;  // 192^-0.5

  const unsigned short* qp = qb + (((size_t)b * S_ + (qt << 6) + (w << 4) + lm) * NH_ + h) * QHD_;
  bf16x8 qf[6];
#pragma unroll
  for (int s = 0; s < 6; ++s) qf[s] = *(const bf16x8*)(qp + s * 32 + (lq << 3));

  const floatx4 vzero = {0.f, 0.f, 0.f, 0.f};
  floatx4 of[8];
#pragma unroll
  for (int i = 0; i < 8; ++i) of[i] = vzero;
  float mrow[4] = {-1e30f, -1e30f, -1e30f, -1e30f};
  float lrow[4] = {0.f, 0.f, 0.f, 0.f};

  const unsigned short* kvbase = kvb + (size_t)(b * NH_ + h) * S_ * 256;
  const unsigned short* kpbase = kpe + (size_t)b * S_ * 64;

  // prefetch registers for one K/V tile (10 uint4 = 40 VGPR)
  uint4 pKa[4], pKp[2], pVa[2], pVb[2];
  auto load_tile = [&](int kt2) {
    const unsigned short* kvt = kvbase + (size_t)(kt2 << 6) * 256;
    const unsigned short* kpt = kpbase + (size_t)(kt2 << 6) * 64;
#pragma unroll
    for (int it = 0; it < 4; ++it) {
      const int c = it * 256 + t;
      pKa[it] = *(const uint4*)(kvt + (c >> 4) * 256 + ((c & 15) << 3));
    }
#pragma unroll
    for (int it = 0; it < 2; ++it) {
      const int c = it * 256 + t;
      pKp[it] = *(const uint4*)(kpt + (c >> 3) * 64 + ((c & 7) << 3));
    }
#pragma unroll
    for (int it = 0; it < 2; ++it) {
      const int idx = it * 256 + t;
      const unsigned short* p0 = kvt + ((idx >> 4) << 1) * 256 + 128 + ((idx & 15) << 3);
      pVa[it] = *(const uint4*)p0;
      pVb[it] = *(const uint4*)(p0 + 256);
    }
  };
  load_tile(0);

  for (int kt = 0; kt <= qt; ++kt) {
    __syncthreads();
    // ---- regs -> LDS (only LDS-write latency between the barriers) ----
#pragma unroll
    for (int it = 0; it < 4; ++it) {
      const int c = it * 256 + t;
      *(uint4*)&Ks[(c >> 4) * 200 + ((c & 15) << 3)] = pKa[it];
    }
#pragma unroll
    for (int it = 0; it < 2; ++it) {
      const int c = it * 256 + t;
      *(uint4*)&Ks[(c >> 3) * 200 + 128 + ((c & 7) << 3)] = pKp[it];
    }
#pragma unroll
    for (int it = 0; it < 2; ++it) {
      const int idx = it * 256 + t;
      const int cg = idx & 15, kp = idx >> 4;
      const unsigned short* ap = (const unsigned short*)&pVa[it];
      const unsigned short* bp = (const unsigned short*)&pVb[it];
#pragma unroll
      for (int i = 0; i < 8; ++i) {
        const int vd = (cg << 3) + i;
        const int sc = (kp ^ ((cg & 7) << 2)) << 1;  // swizzled dword col -> shorts
        *(unsigned int*)&Vt[vd * 72 + sc] =
            (unsigned int)ap[i] | ((unsigned int)bp[i] << 16);
      }
    }
    __syncthreads();
    // ---- issue next tile's global loads; they drain under compute ----
    if (kt < qt) load_tile(kt + 1);

    const bool diag = (kt == qt);
    const int nimax = diag ? w : 3;

    floatx4 sacc[4];
#pragma unroll
    for (int ni = 0; ni < 4; ++ni) sacc[ni] = vzero;
    for (int ni = 0; ni <= nimax; ++ni) {
#pragma unroll
      for (int s = 0; s < 6; ++s) {
        const bf16x8 kf = *(const bf16x8*)&Ks[(ni * 16 + lm) * 200 + s * 32 + (lq << 3)];
        sacc[ni] = __builtin_amdgcn_mfma_f32_16x16x32_bf16(qf[s], kf, sacc[ni], 0, 0, 0);
      }
    }

#pragma unroll
    for (int r = 0; r < 4; ++r) {
      const int rq = (lq << 2) + r;
      float sc[4], mx = -1e30f;
#pragma unroll
      for (int ni = 0; ni < 4; ++ni) {
        float v = sacc[ni][r] * SCALE;
        if (ni > nimax) v = -1e30f;
        if (diag && ni == w && lm > rq) v = -1e30f;
        sc[ni] = v;
        mx = fmaxf(mx, v);
      }
#pragma unroll
      for (int off = 8; off; off >>= 1) mx = fmaxf(mx, __shfl_xor(mx, off));
      const float mnew = fmaxf(mrow[r], mx);
      const float al = __expf(mrow[r] - mnew);
      mrow[r] = mnew;
      float ps = 0.f;
#pragma unroll
      for (int ni = 0; ni < 4; ++ni) {
        const float p = __expf(sc[ni] - mnew);
        ps += p;
        Ps[(w * 16 + rq) * 72 + ni * 16 + lm] = f2bf(p);
      }
#pragma unroll
      for (int off = 8; off; off >>= 1) ps += __shfl_xor(ps, off);
      lrow[r] = lrow[r] * al + ps;
#pragma unroll
      for (int vt = 0; vt < 8; ++vt) of[vt][r] *= al;
    }

    const int ksmax = diag ? ((w >= 2) ? 1 : 0) : 1;
    for (int ks2 = 0; ks2 <= ksmax; ++ks2) {
      const bf16x8 pf = *(const bf16x8*)&Ps[(w * 16 + lm) * 72 + ks2 * 32 + (lq << 3)];
#pragma unroll
      for (int vt = 0; vt < 8; ++vt) {
        const int rr = vt * 16 + lm;
        const int c0 = (ks2 << 4) + (lq << 2);  // dword col
        const bf16x8 vf = *(const bf16x8*)&Vt[rr * 72 + ((c0 ^ (((rr >> 3) & 7) << 2)) << 1)];
        of[vt] = __builtin_amdgcn_mfma_f32_16x16x32_bf16(pf, vf, of[vt], 0, 0, 0);
      }
    }
  }

#pragma unroll
  for (int r = 0; r < 4; ++r) {
    const int qrow = (qt << 6) + (w << 4) + (lq << 2) + r;
    const float inv = 1.f / lrow[r];
    unsigned short* orow = o + ((size_t)b * S_ + qrow) * 4096 + h * 128;
#pragma unroll
    for (int vt = 0; vt < 8; ++vt)
      orow[vt * 16 + lm] = f2bf(of[vt][r] * inv);
  }
}

// ---------------------------------------------------------------------------
extern "C" void kernel_launch(void* const* d_in, const int* in_sizes, int n_in,
                              void* d_out, int out_size, void* d_ws, size_t ws_size,
                              hipStream_t stream) {
  (void)in_sizes; (void)n_in; (void)out_size; (void)ws_size;
  const float* hs   = (const float*)d_in[0];
  const float* cosp = (const float*)d_in[1];
  const float* sinp = (const float*)d_in[2];
  const int*   pos  = (const int*)d_in[3];
  const float* Wqa  = (const float*)d_in[4];
  const float* gqa  = (const float*)d_in[5];
  const float* bqa  = (const float*)d_in[6];
  const float* Wqb  = (const float*)d_in[7];
  const float* Wkva = (const float*)d_in[8];
  const float* gkva = (const float*)d_in[9];
  const float* bkva = (const float*)d_in[10];
  const float* Wkvb = (const float*)d_in[11];
  const float* Wo   = (const float*)d_in[12];
  float* out = (float*)d_out;

  char* ws = (char*)d_ws;
  // lifetime-aliased workspace (~204.5 MiB total)
  unsigned short* hsb   = (unsigned short*)(ws);               // 33,554,432
  float*          q_a   = (float*)(ws + 33554432);             // 25,165,824
  unsigned short* qb    = (unsigned short*)(ws);               // alias over hsb+q_a (50,331,648 <= 58,720,256)
  unsigned short* WqaT  = (unsigned short*)(ws + 58720256);    // 12,582,912 (1536x4096)
  unsigned short* WkvaT = (unsigned short*)(ws + 71303168);    //  5,242,880 (640x4096, rows 576+ poison)
  unsigned short* qln   = (unsigned short*)(ws + 58720256);    // alias over WqaT (12,582,912)
  unsigned short* kvln  = (unsigned short*)(ws + 71303168);    // alias over WkvaT (4,194,304)
  unsigned short* WqbT  = (unsigned short*)(ws + 76546048);    // 18,874,368 (6144x1536)
  float*          ckv   = (float*)(ws + 95420416);             //  9,437,184
  unsigned short* WkvbT = (unsigned short*)(ws + 104857600);   //  8,388,608 (8192x512)
  unsigned short* ob    = (unsigned short*)(ws + 76546048);    // alias over WqbT+ckv+WkvbT (33,554,432 <= 36,700,160)
  unsigned short* WoT   = (unsigned short*)(ws + 113246208);   // 33,554,432 (4096x4096)
  unsigned short* kvb   = (unsigned short*)(ws + 146800640);   // 67,108,864 (B,NH,S,256)
  unsigned short* kpe   = (unsigned short*)(ws + 213909504);   //    524,288

  const dim3 blk(256);
  // prepass: bf16 convert + weight transposes
  convert_kernel<<<dim3(8192), blk, 0, stream>>>(hs, hsb);
  transpose_kernel<<<dim3(48, 128), blk, 0, stream>>>(Wqa, WqaT, 4096, 1536);
  transpose_kernel<<<dim3(18, 128), blk, 0, stream>>>(Wkva, WkvaT, 4096, 576);
  transpose_kernel<<<dim3(192, 48), blk, 0, stream>>>(Wqb, WqbT, 1536, 6144);
  transpose_kernel<<<dim3(256, 16), blk, 0, stream>>>(Wkvb, WkvbT, 512, 8192);
  transpose_kernel<<<dim3(128, 128), blk, 0, stream>>>(Wo, WoT, 4096, 4096);

  // q_a = hs @ Wqa ; ckv = hs @ Wkva
  gemm_bt<0><<<dim3(32, 12), blk, 0, stream>>>(hsb, WqaT, q_a, 1536, 4096, 4096, 4096, 1536);
  gemm_bt<0><<<dim3(32, 5), blk, 0, stream>>>(hsb, WkvaT, ckv, 576, 4096, 4096, 4096, 576);
  // LN -> bf16 (qln over WqaT, kvln over WkvaT — both weights dead now)
  ln_kernel<<<dim3(4096), blk, 0, stream>>>(q_a, gqa, bqa, qln, 1536, 1536, 1536);
  ln_kernel<<<dim3(4096), blk, 0, stream>>>(ckv, gkva, bkva, kvln, 512, 576, 512);
  rope_k_kernel<<<dim3(512), blk, 0, stream>>>(ckv, cosp, sinp, pos, kpe);
  // qb = qln @ Wqb (qb over hsb+q_a — both dead now)
  gemm_bt<1><<<dim3(32, 48), blk, 0, stream>>>(qln, WqbT, qb, 6144, 1536, 1536, 1536, 6144);
  rope_q_kernel<<<dim3(16384), blk, 0, stream>>>(qb, cosp, sinp, pos);
  // kvb = kvln @ Wkvb, scattered to (B,NH,S,256)
  gemm_bt<2><<<dim3(32, 64), blk, 0, stream>>>(kvln, WkvbT, kvb, 8192, 512, 512, 512, 8192);
  // attention (ob over WqbT+ckv+WkvbT — all dead now)
  attn_kernel<<<dim3(16, 32, 4), blk, 0, stream>>>(qb, kvb, kpe, ob);
  // out = ob @ Wo
  gemm_bt<0><<<dim3(32, 32), blk, 0, stream>>>(ob, WoT, out, 4096, 4096, 4096, 4096, 4096);
}

// Round 2
// 1041.023 us; speedup vs baseline: 1.0992x; 1.0906x over previous
//
#include <hip/hip_runtime.h>

// MLA shapes (fixed)
#define B_ 4
#define S_ 1024
#define H_ 4096
#define NH_ 32
#define QHD_ 192
#define EPS_ 1e-6f

typedef __bf16 bf16x8 __attribute__((ext_vector_type(8)));
typedef float floatx4 __attribute__((ext_vector_type(4)));

__device__ __forceinline__ unsigned short f2bf(float f) {
  unsigned int u = __builtin_bit_cast(unsigned int, f);
  u += 0x7fffu + ((u >> 16) & 1u);   // round-to-nearest-even (finite data only)
  return (unsigned short)(u >> 16);
}
__device__ __forceinline__ float bf2f(unsigned short s) {
  return __builtin_bit_cast(float, ((unsigned int)s) << 16);
}

// async global->LDS, 16B per lane; LDS dest = wave-uniform base + lane*16 (m104)
__device__ __forceinline__ void gload16(const unsigned short* g, unsigned short* l) {
  __builtin_amdgcn_global_load_lds(
      (const __attribute__((address_space(1))) void*)g,
      (__attribute__((address_space(3))) void*)l, 16, 0, 0);
}

// ---------------------------------------------------------------------------
// fp32 -> bf16 convert (hs), 8 elems/thread
// ---------------------------------------------------------------------------
__global__ __launch_bounds__(256) void convert_kernel(
    const float* __restrict__ x, unsigned short* __restrict__ y)
{
  const int i = (blockIdx.x * 256 + threadIdx.x) * 8;
  const float4 a = *(const float4*)(x + i);
  const float4 b = *(const float4*)(x + i + 4);
  ushort4 u, v;
  u.x = f2bf(a.x); u.y = f2bf(a.y); u.z = f2bf(a.z); u.w = f2bf(a.w);
  v.x = f2bf(b.x); v.y = f2bf(b.y); v.z = f2bf(b.z); v.w = f2bf(b.w);
  *(ushort4*)(y + i) = u;
  *(ushort4*)(y + i + 4) = v;
}

// ---------------------------------------------------------------------------
// W (KxN fp32 row-major) -> Wt (NxK bf16 row-major). 32x32 LDS tiles.
// ---------------------------------------------------------------------------
__global__ __launch_bounds__(256) void transpose_kernel(
    const float* __restrict__ W, unsigned short* __restrict__ Wt,
    const int K, const int N)
{
  __shared__ float tile[32][33];
  const int tx = threadIdx.x & 31, ty = threadIdx.x >> 5;
  const int nb = blockIdx.x << 5, kb = blockIdx.y << 5;
#pragma unroll
  for (int j = 0; j < 4; ++j)
    tile[ty + j * 8][tx] = W[(size_t)(kb + ty + j * 8) * N + nb + tx];
  __syncthreads();
#pragma unroll
  for (int j = 0; j < 4; ++j)
    Wt[(size_t)(nb + ty + j * 8) * K + kb + tx] = f2bf(tile[tx][ty + j * 8]);
}

// ---------------------------------------------------------------------------
// m97-class GEMM: C(MxN) = A(MxK) @ Bt(NxK)^T, both bf16, staged via
// global_load_lds width=16 into unpadded LDS [128][32]. 128x128 tile, BK=32,
// 4 waves (2x2 of 64x64), mfma_f32_16x16x32_bf16.
// OMODE: 0 = fp32 row-major, 1 = bf16 row-major, 2 = bf16 (B,NH,S,256) kv.
// M%128==0, K%32==0; Bt rows padded to 128-mult (pad contents finite poison).
// ---------------------------------------------------------------------------
template<int OMODE>
__global__ __launch_bounds__(256, 2) void gemm_bt(
    const unsigned short* __restrict__ A, const unsigned short* __restrict__ Bt,
    void* __restrict__ Cv, const int N, const int K,
    const int lda, const int ldb, const int ldc)
{
  __shared__ unsigned short As[128 * 32];
  __shared__ unsigned short Bs[128 * 32];

  const int t = threadIdx.x;
  const int m0 = blockIdx.x * 128, n0 = blockIdx.y * 128;
  const int w = t >> 6, lane = t & 63;
  const int wm = (w >> 1) << 6, wn = (w & 1) << 6;
  const int lm = lane & 15, lq = lane >> 4;

  const floatx4 vzero = {0.f, 0.f, 0.f, 0.f};
  floatx4 acc[4][4];
#pragma unroll
  for (int i = 0; i < 4; ++i)
#pragma unroll
    for (int j = 0; j < 4; ++j) acc[i][j] = vzero;

  // staging: wave w does calls i=0,1; call covers 16 rows x 32 cols (1 KB).
  // lane -> row (w*32 + i*16 + lane/4), chunk kc = lane&3 (8 shorts).
  const int srow = (w << 5) + (lane >> 2);
  const int skc = (lane & 3) << 3;
  const unsigned short* gA = A + (size_t)(m0 + srow) * lda + skc;
  const unsigned short* gB = Bt + (size_t)(n0 + srow) * ldb + skc;
  unsigned short* lA0 = &As[(w << 1) * 512];
  unsigned short* lA1 = &As[((w << 1) + 1) * 512];
  unsigned short* lB0 = &Bs[(w << 1) * 512];
  unsigned short* lB1 = &Bs[((w << 1) + 1) * 512];

  const int nk = K >> 5;
  for (int kb = 0; kb < nk; ++kb) {
    const int k0 = kb << 5;
    __syncthreads();
    gload16(gA + k0, lA0);
    gload16(gA + (size_t)16 * lda + k0, lA1);
    gload16(gB + k0, lB0);
    gload16(gB + (size_t)16 * ldb + k0, lB1);
    __syncthreads();

    bf16x8 af[4], bfr[4];
#pragma unroll
    for (int mi = 0; mi < 4; ++mi)
      af[mi] = *(const bf16x8*)&As[(wm + mi * 16 + lm) * 32 + (lq << 3)];
#pragma unroll
    for (int ni = 0; ni < 4; ++ni)
      bfr[ni] = *(const bf16x8*)&Bs[(wn + ni * 16 + lm) * 32 + (lq << 3)];
#pragma unroll
    for (int mi = 0; mi < 4; ++mi)
#pragma unroll
      for (int ni = 0; ni < 4; ++ni)
        acc[mi][ni] = __builtin_amdgcn_mfma_f32_16x16x32_bf16(af[mi], bfr[ni], acc[mi][ni], 0, 0, 0);
  }

#pragma unroll
  for (int mi = 0; mi < 4; ++mi) {
    const int row = m0 + wm + mi * 16 + (lq << 2);
#pragma unroll
    for (int ni = 0; ni < 4; ++ni) {
      const int col = n0 + wn + ni * 16 + lm;
      if (col < N) {
#pragma unroll
        for (int r = 0; r < 4; ++r) {
          if constexpr (OMODE == 0)
            ((float*)Cv)[(size_t)(row + r) * ldc + col] = acc[mi][ni][r];
          else if constexpr (OMODE == 1)
            ((unsigned short*)Cv)[(size_t)(row + r) * ldc + col] = f2bf(acc[mi][ni][r]);
          else {
            const int rr2 = row + r;  // (B,NH,S,256): h=col>>8, d=col&255
            ((unsigned short*)Cv)[(((size_t)(rr2 >> 10) * NH_ + (col >> 8)) * S_ + (rr2 & 1023)) * 256 + (col & 255)] = f2bf(acc[mi][ni][r]);
          }
        }
      }
    }
  }
}

// ---------------------------------------------------------------------------
// LayerNorm: x fp32 rows (len L, stride xstride) -> y bf16 (stride ystride).
// ---------------------------------------------------------------------------
__global__ __launch_bounds__(256) void ln_kernel(
    const float* __restrict__ x, const float* __restrict__ g,
    const float* __restrict__ bias, unsigned short* __restrict__ y,
    const int L, const int xstride, const int ystride)
{
  __shared__ float sh[4];
  const int t = threadIdx.x;
  const float* xr = x + (size_t)blockIdx.x * xstride;
  unsigned short* yr = y + (size_t)blockIdx.x * ystride;
  const int n = L >> 8;
  float vals[6];
  float s = 0.f;
  for (int i = 0; i < n; ++i) { vals[i] = xr[t + (i << 8)]; s += vals[i]; }
#pragma unroll
  for (int off = 32; off; off >>= 1) s += __shfl_down(s, off);
  if ((t & 63) == 0) sh[t >> 6] = s;
  __syncthreads();
  const float mean = (sh[0] + sh[1] + sh[2] + sh[3]) / (float)L;
  float vs = 0.f;
  for (int i = 0; i < n; ++i) { const float d = vals[i] - mean; vs += d * d; }
#pragma unroll
  for (int off = 32; off; off >>= 1) vs += __shfl_down(vs, off);
  __syncthreads();
  if ((t & 63) == 0) sh[t >> 6] = vs;
  __syncthreads();
  const float inv = rsqrtf((sh[0] + sh[1] + sh[2] + sh[3]) / (float)L + EPS_);
  for (int i = 0; i < n; ++i) {
    const int c = t + (i << 8);
    yr[c] = f2bf((vals[i] - mean) * inv * g[c] + bias[c]);
  }
}

// ---------------------------------------------------------------------------
// RoPE on q_pe (cols 128..191 of each 192-wide head), in place on bf16 q.
// ---------------------------------------------------------------------------
__global__ __launch_bounds__(256) void rope_q_kernel(
    unsigned short* __restrict__ q, const float* __restrict__ cosp,
    const float* __restrict__ sinp, const int* __restrict__ pos)
{
  const int i = blockIdx.x * 256 + threadIdx.x;  // B*S*NH*32
  const int p = i & 31;
  const int h = (i >> 5) & 31;
  const int bs = i >> 10;
  const int pid = pos[bs];
  const size_t base = ((size_t)bs * NH_ + h) * QHD_ + 128;
  const float x1 = bf2f(q[base + p]);
  const float x2 = bf2f(q[base + p + 32]);
  const float* cr = cosp + (size_t)pid * 64;
  const float* sr = sinp + (size_t)pid * 64;
  q[base + p]      = f2bf(x1 * cr[p] - x2 * sr[p]);
  q[base + p + 32] = f2bf(x2 * cr[p + 32] + x1 * sr[p + 32]);
}

// RoPE on k_pe: ckv cols 512..575 (fp32) -> kpe bf16 (B,S,64)
__global__ __launch_bounds__(256) void rope_k_kernel(
    const float* __restrict__ ckv, const float* __restrict__ cosp,
    const float* __restrict__ sinp, const int* __restrict__ pos,
    unsigned short* __restrict__ kpe)
{
  const int i = blockIdx.x * 256 + threadIdx.x;  // B*S*32
  const int p = i & 31;
  const int bs = i >> 5;
  const int pid = pos[bs];
  const float* row = ckv + (size_t)bs * 576 + 512;
  const float x1 = row[p], x2 = row[p + 32];
  const float* cr = cosp + (size_t)pid * 64;
  const float* sr = sinp + (size_t)pid * 64;
  kpe[(size_t)bs * 64 + p]      = f2bf(x1 * cr[p] - x2 * sr[p]);
  kpe[(size_t)bs * 64 + p + 32] = f2bf(x2 * cr[p + 32] + x1 * sr[p + 32]);
}

// ---------------------------------------------------------------------------
// MFMA flash attention. Block = 4 waves = (b,h,64 q).
// Round-2 changes:
//  (a) __launch_bounds__(256, 3): LDS (53248B) caps occupancy at 3 blocks/CU
//      = 3 waves/SIMD anyway, so let the register allocator use up to
//      512/3 = 170 VGPR. Round-1's prefetch regs (40 VGPR) spilled to
//      scratch under the default ~128 budget (WRITE_SIZE 33MB -> 230MB,
//      scratch-read latency between the barriers) — this un-spills them
//      so the T14 async-STAGE actually hides global latency under compute.
//  (b) base-2 softmax: scores pre-scaled by SCALE*log2(e), v_exp_f32 used
//      directly (saves one VALU mul per exp; 16 exp/thread/tile).
//  (c) Vt XOR-swizzle (round-1): dword col ^= ((row>>3)&7)<<2.
// ---------------------------------------------------------------------------
__global__ __launch_bounds__(256, 3) void attn_kernel(
    const unsigned short* __restrict__ qb, const unsigned short* __restrict__ kvb,
    const unsigned short* __restrict__ kpe, unsigned short* __restrict__ o)
{
  __shared__ unsigned short Ks[64 * 200];      // [k][d 0..191], stride 200
  __shared__ unsigned short Vt[128 * 72];      // [vd][k], stride 72, swizzled cols
  __shared__ unsigned short Ps[4 * 16 * 72];   // per-wave [m][k], stride 72

  const int t = threadIdx.x;
  const int qt = (int)gridDim.x - 1 - (int)blockIdx.x;  // longest first
  const int h = blockIdx.y, b = blockIdx.z;
  const int w = t >> 6, lane = t & 63;
  const int lm = lane & 15, lq = lane >> 4;
  const float SCALE2 = 0.10411754645f;  // 192^-0.5 * log2(e)

  const unsigned short* qp = qb + (((size_t)b * S_ + (qt << 6) + (w << 4) + lm) * NH_ + h) * QHD_;
  bf16x8 qf[6];
#pragma unroll
  for (int s = 0; s < 6; ++s) qf[s] = *(const bf16x8*)(qp + s * 32 + (lq << 3));

  const floatx4 vzero = {0.f, 0.f, 0.f, 0.f};
  floatx4 of[8];
#pragma unroll
  for (int i = 0; i < 8; ++i) of[i] = vzero;
  float mrow[4] = {-1e30f, -1e30f, -1e30f, -1e30f};
  float lrow[4] = {0.f, 0.f, 0.f, 0.f};

  const unsigned short* kvbase = kvb + (size_t)(b * NH_ + h) * S_ * 256;
  const unsigned short* kpbase = kpe + (size_t)b * S_ * 64;

  // prefetch registers for one K/V tile (10 uint4 = 40 VGPR)
  uint4 pKa[4], pKp[2], pVa[2], pVb[2];
  auto load_tile = [&](int kt2) {
    const unsigned short* kvt = kvbase + (size_t)(kt2 << 6) * 256;
    const unsigned short* kpt = kpbase + (size_t)(kt2 << 6) * 64;
#pragma unroll
    for (int it = 0; it < 4; ++it) {
      const int c = it * 256 + t;
      pKa[it] = *(const uint4*)(kvt + (c >> 4) * 256 + ((c & 15) << 3));
    }
#pragma unroll
    for (int it = 0; it < 2; ++it) {
      const int c = it * 256 + t;
      pKp[it] = *(const uint4*)(kpt + (c >> 3) * 64 + ((c & 7) << 3));
    }
#pragma unroll
    for (int it = 0; it < 2; ++it) {
      const int idx = it * 256 + t;
      const unsigned short* p0 = kvt + ((idx >> 4) << 1) * 256 + 128 + ((idx & 15) << 3);
      pVa[it] = *(const uint4*)p0;
      pVb[it] = *(const uint4*)(p0 + 256);
    }
  };
  load_tile(0);

  for (int kt = 0; kt <= qt; ++kt) {
    __syncthreads();
    // ---- regs -> LDS (only LDS-write latency between the barriers) ----
#pragma unroll
    for (int it = 0; it < 4; ++it) {
      const int c = it * 256 + t;
      *(uint4*)&Ks[(c >> 4) * 200 + ((c & 15) << 3)] = pKa[it];
    }
#pragma unroll
    for (int it = 0; it < 2; ++it) {
      const int c = it * 256 + t;
      *(uint4*)&Ks[(c >> 3) * 200 + 128 + ((c & 7) << 3)] = pKp[it];
    }
#pragma unroll
    for (int it = 0; it < 2; ++it) {
      const int idx = it * 256 + t;
      const int cg = idx & 15, kp = idx >> 4;
      const unsigned short* ap = (const unsigned short*)&pVa[it];
      const unsigned short* bp = (const unsigned short*)&pVb[it];
#pragma unroll
      for (int i = 0; i < 8; ++i) {
        const int vd = (cg << 3) + i;
        const int sc = (kp ^ ((cg & 7) << 2)) << 1;  // swizzled dword col -> shorts
        *(unsigned int*)&Vt[vd * 72 + sc] =
            (unsigned int)ap[i] | ((unsigned int)bp[i] << 16);
      }
    }
    __syncthreads();
    // ---- issue next tile's global loads; they drain under compute ----
    if (kt < qt) load_tile(kt + 1);

    const bool diag = (kt == qt);
    const int nimax = diag ? w : 3;

    floatx4 sacc[4];
#pragma unroll
    for (int ni = 0; ni < 4; ++ni) sacc[ni] = vzero;
    for (int ni = 0; ni <= nimax; ++ni) {
#pragma unroll
      for (int s = 0; s < 6; ++s) {
        const bf16x8 kf = *(const bf16x8*)&Ks[(ni * 16 + lm) * 200 + s * 32 + (lq << 3)];
        sacc[ni] = __builtin_amdgcn_mfma_f32_16x16x32_bf16(qf[s], kf, sacc[ni], 0, 0, 0);
      }
    }

#pragma unroll
    for (int r = 0; r < 4; ++r) {
      const int rq = (lq << 2) + r;
      float sc[4], mx = -1e30f;
#pragma unroll
      for (int ni = 0; ni < 4; ++ni) {
        float v = sacc[ni][r] * SCALE2;   // base-2 domain
        if (ni > nimax) v = -1e30f;
        if (diag && ni == w && lm > rq) v = -1e30f;
        sc[ni] = v;
        mx = fmaxf(mx, v);
      }
#pragma unroll
      for (int off = 8; off; off >>= 1) mx = fmaxf(mx, __shfl_xor(mx, off));
      const float mnew = fmaxf(mrow[r], mx);
      const float al = __builtin_amdgcn_exp2f(mrow[r] - mnew);
      mrow[r] = mnew;
      float ps = 0.f;
#pragma unroll
      for (int ni = 0; ni < 4; ++ni) {
        const float p = __builtin_amdgcn_exp2f(sc[ni] - mnew);
        ps += p;
        Ps[(w * 16 + rq) * 72 + ni * 16 + lm] = f2bf(p);
      }
#pragma unroll
      for (int off = 8; off; off >>= 1) ps += __shfl_xor(ps, off);
      lrow[r] = lrow[r] * al + ps;
#pragma unroll
      for (int vt = 0; vt < 8; ++vt) of[vt][r] *= al;
    }

    const int ksmax = diag ? ((w >= 2) ? 1 : 0) : 1;
    for (int ks2 = 0; ks2 <= ksmax; ++ks2) {
      const bf16x8 pf = *(const bf16x8*)&Ps[(w * 16 + lm) * 72 + ks2 * 32 + (lq << 3)];
#pragma unroll
      for (int vt = 0; vt < 8; ++vt) {
        const int rr = vt * 16 + lm;
        const int c0 = (ks2 << 4) + (lq << 2);  // dword col
        const bf16x8 vf = *(const bf16x8*)&Vt[rr * 72 + ((c0 ^ (((rr >> 3) & 7) << 2)) << 1)];
        of[vt] = __builtin_amdgcn_mfma_f32_16x16x32_bf16(pf, vf, of[vt], 0, 0, 0);
      }
    }
  }

#pragma unroll
  for (int r = 0; r < 4; ++r) {
    const int qrow = (qt << 6) + (w << 4) + (lq << 2) + r;
    const float inv = 1.f / lrow[r];
    unsigned short* orow = o + ((size_t)b * S_ + qrow) * 4096 + h * 128;
#pragma unroll
    for (int vt = 0; vt < 8; ++vt)
      orow[vt * 16 + lm] = f2bf(of[vt][r] * inv);
  }
}

// ---------------------------------------------------------------------------
extern "C" void kernel_launch(void* const* d_in, const int* in_sizes, int n_in,
                              void* d_out, int out_size, void* d_ws, size_t ws_size,
                              hipStream_t stream) {
  (void)in_sizes; (void)n_in; (void)out_size; (void)ws_size;
  const float* hs   = (const float*)d_in[0];
  const float* cosp = (const float*)d_in[1];
  const float* sinp = (const float*)d_in[2];
  const int*   pos  = (const int*)d_in[3];
  const float* Wqa  = (const float*)d_in[4];
  const float* gqa  = (const float*)d_in[5];
  const float* bqa  = (const float*)d_in[6];
  const float* Wqb  = (const float*)d_in[7];
  const float* Wkva = (const float*)d_in[8];
  const float* gkva = (const float*)d_in[9];
  const float* bkva = (const float*)d_in[10];
  const float* Wkvb = (const float*)d_in[11];
  const float* Wo   = (const float*)d_in[12];
  float* out = (float*)d_out;

  char* ws = (char*)d_ws;
  // lifetime-aliased workspace (~204.5 MiB total)
  unsigned short* hsb   = (unsigned short*)(ws);               // 33,554,432
  float*          q_a   = (float*)(ws + 33554432);             // 25,165,824
  unsigned short* qb    = (unsigned short*)(ws);               // alias over hsb+q_a (50,331,648 <= 58,720,256)
  unsigned short* WqaT  = (unsigned short*)(ws + 58720256);    // 12,582,912 (1536x4096)
  unsigned short* WkvaT = (unsigned short*)(ws + 71303168);    //  5,242,880 (640x4096, rows 576+ poison)
  unsigned short* qln   = (unsigned short*)(ws + 58720256);    // alias over WqaT (12,582,912)
  unsigned short* kvln  = (unsigned short*)(ws + 71303168);    // alias over WkvaT (4,194,304)
  unsigned short* WqbT  = (unsigned short*)(ws + 76546048);    // 18,874,368 (6144x1536)
  float*          ckv   = (float*)(ws + 95420416);             //  9,437,184
  unsigned short* WkvbT = (unsigned short*)(ws + 104857600);   //  8,388,608 (8192x512)
  unsigned short* ob    = (unsigned short*)(ws + 76546048);    // alias over WqbT+ckv+WkvbT (33,554,432 <= 36,700,160)
  unsigned short* WoT   = (unsigned short*)(ws + 113246208);   // 33,554,432 (4096x4096)
  unsigned short* kvb   = (unsigned short*)(ws + 146800640);   // 67,108,864 (B,NH,S,256)
  unsigned short* kpe   = (unsigned short*)(ws + 213909504);   //    524,288

  const dim3 blk(256);
  // prepass: bf16 convert + weight transposes
  convert_kernel<<<dim3(8192), blk, 0, stream>>>(hs, hsb);
  transpose_kernel<<<dim3(48, 128), blk, 0, stream>>>(Wqa, WqaT, 4096, 1536);
  transpose_kernel<<<dim3(18, 128), blk, 0, stream>>>(Wkva, WkvaT, 4096, 576);
  transpose_kernel<<<dim3(192, 48), blk, 0, stream>>>(Wqb, WqbT, 1536, 6144);
  transpose_kernel<<<dim3(256, 16), blk, 0, stream>>>(Wkvb, WkvbT, 512, 8192);
  transpose_kernel<<<dim3(128, 128), blk, 0, stream>>>(Wo, WoT, 4096, 4096);

  // q_a = hs @ Wqa ; ckv = hs @ Wkva
  gemm_bt<0><<<dim3(32, 12), blk, 0, stream>>>(hsb, WqaT, q_a, 1536, 4096, 4096, 4096, 1536);
  gemm_bt<0><<<dim3(32, 5), blk, 0, stream>>>(hsb, WkvaT, ckv, 576, 4096, 4096, 4096, 576);
  // LN -> bf16 (qln over WqaT, kvln over WkvaT — both weights dead now)
  ln_kernel<<<dim3(4096), blk, 0, stream>>>(q_a, gqa, bqa, qln, 1536, 1536, 1536);
  ln_kernel<<<dim3(4096), blk, 0, stream>>>(ckv, gkva, bkva, kvln, 512, 576, 512);
  rope_k_kernel<<<dim3(512), blk, 0, stream>>>(ckv, cosp, sinp, pos, kpe);
  // qb = qln @ Wqb (qb over hsb+q_a — both dead now)
  gemm_bt<1><<<dim3(32, 48), blk, 0, stream>>>(qln, WqbT, qb, 6144, 1536, 1536, 1536, 6144);
  rope_q_kernel<<<dim3(16384), blk, 0, stream>>>(qb, cosp, sinp, pos);
  // kvb = kvln @ Wkvb, scattered to (B,NH,S,256)
  gemm_bt<2><<<dim3(32, 64), blk, 0, stream>>>(kvln, WkvbT, kvb, 8192, 512, 512, 512, 8192);
  // attention (ob over WqbT+ckv+WkvbT — all dead now)
  attn_kernel<<<dim3(16, 32, 4), blk, 0, stream>>>(qb, kvb, kpe, ob);
  // out = ob @ Wo
  gemm_bt<0><<<dim3(32, 32), blk, 0, stream>>>(ob, WoT, out, 4096, 4096, 4096, 4096, 4096);
}

// Round 3
// 983.351 us; speedup vs baseline: 1.1637x; 1.0586x over previous
//
#include <hip/hip_runtime.h>

// MLA shapes (fixed)
#define B_ 4
#define S_ 1024
#define H_ 4096
#define NH_ 32
#define QHD_ 192
#define EPS_ 1e-6f

typedef __bf16 bf16x8 __attribute__((ext_vector_type(8)));
typedef float floatx4 __attribute__((ext_vector_type(4)));

__device__ __forceinline__ unsigned short f2bf(float f) {
  unsigned int u = __builtin_bit_cast(unsigned int, f);
  u += 0x7fffu + ((u >> 16) & 1u);   // round-to-nearest-even (finite data only)
  return (unsigned short)(u >> 16);
}
__device__ __forceinline__ float bf2f(unsigned short s) {
  return __builtin_bit_cast(float, ((unsigned int)s) << 16);
}

// async global->LDS, 16B per lane; LDS dest = wave-uniform base + lane*16 (m104)
__device__ __forceinline__ void gload16(const unsigned short* g, unsigned short* l) {
  __builtin_amdgcn_global_load_lds(
      (const __attribute__((address_space(1))) void*)g,
      (__attribute__((address_space(3))) void*)l, 16, 0, 0);
}

// ---------------------------------------------------------------------------
// fp32 -> bf16 convert (hs), 8 elems/thread
// ---------------------------------------------------------------------------
__global__ __launch_bounds__(256) void convert_kernel(
    const float* __restrict__ x, unsigned short* __restrict__ y)
{
  const int i = (blockIdx.x * 256 + threadIdx.x) * 8;
  const float4 a = *(const float4*)(x + i);
  const float4 b = *(const float4*)(x + i + 4);
  ushort4 u, v;
  u.x = f2bf(a.x); u.y = f2bf(a.y); u.z = f2bf(a.z); u.w = f2bf(a.w);
  v.x = f2bf(b.x); v.y = f2bf(b.y); v.z = f2bf(b.z); v.w = f2bf(b.w);
  *(ushort4*)(y + i) = u;
  *(ushort4*)(y + i + 4) = v;
}

// ---------------------------------------------------------------------------
// W (KxN fp32 row-major) -> Wt (NxK bf16 row-major). 32x32 LDS tiles.
// ---------------------------------------------------------------------------
__global__ __launch_bounds__(256) void transpose_kernel(
    const float* __restrict__ W, unsigned short* __restrict__ Wt,
    const int K, const int N)
{
  __shared__ float tile[32][33];
  const int tx = threadIdx.x & 31, ty = threadIdx.x >> 5;
  const int nb = blockIdx.x << 5, kb = blockIdx.y << 5;
#pragma unroll
  for (int j = 0; j < 4; ++j)
    tile[ty + j * 8][tx] = W[(size_t)(kb + ty + j * 8) * N + nb + tx];
  __syncthreads();
#pragma unroll
  for (int j = 0; j < 4; ++j)
    Wt[(size_t)(nb + ty + j * 8) * K + kb + tx] = f2bf(tile[tx][ty + j * 8]);
}

// ---------------------------------------------------------------------------
// m97-class GEMM: C(MxN) = A(MxK) @ Bt(NxK)^T, both bf16, staged via
// global_load_lds width=16 into unpadded LDS [128][32]. 128x128 tile, BK=32,
// 4 waves (2x2 of 64x64), mfma_f32_16x16x32_bf16.
// OMODE: 0 = fp32 row-major, 1 = bf16 row-major, 2 = bf16 (B,NH,S,256) kv.
// M%128==0, K%32==0; Bt rows padded to 128-mult (pad contents finite poison).
// ---------------------------------------------------------------------------
template<int OMODE>
__global__ __launch_bounds__(256, 2) void gemm_bt(
    const unsigned short* __restrict__ A, const unsigned short* __restrict__ Bt,
    void* __restrict__ Cv, const int N, const int K,
    const int lda, const int ldb, const int ldc)
{
  __shared__ unsigned short As[128 * 32];
  __shared__ unsigned short Bs[128 * 32];

  const int t = threadIdx.x;
  const int m0 = blockIdx.x * 128, n0 = blockIdx.y * 128;
  const int w = t >> 6, lane = t & 63;
  const int wm = (w >> 1) << 6, wn = (w & 1) << 6;
  const int lm = lane & 15, lq = lane >> 4;

  const floatx4 vzero = {0.f, 0.f, 0.f, 0.f};
  floatx4 acc[4][4];
#pragma unroll
  for (int i = 0; i < 4; ++i)
#pragma unroll
    for (int j = 0; j < 4; ++j) acc[i][j] = vzero;

  // staging: wave w does calls i=0,1; call covers 16 rows x 32 cols (1 KB).
  // lane -> row (w*32 + i*16 + lane/4), chunk kc = lane&3 (8 shorts).
  const int srow = (w << 5) + (lane >> 2);
  const int skc = (lane & 3) << 3;
  const unsigned short* gA = A + (size_t)(m0 + srow) * lda + skc;
  const unsigned short* gB = Bt + (size_t)(n0 + srow) * ldb + skc;
  unsigned short* lA0 = &As[(w << 1) * 512];
  unsigned short* lA1 = &As[((w << 1) + 1) * 512];
  unsigned short* lB0 = &Bs[(w << 1) * 512];
  unsigned short* lB1 = &Bs[((w << 1) + 1) * 512];

  const int nk = K >> 5;
  for (int kb = 0; kb < nk; ++kb) {
    const int k0 = kb << 5;
    __syncthreads();
    gload16(gA + k0, lA0);
    gload16(gA + (size_t)16 * lda + k0, lA1);
    gload16(gB + k0, lB0);
    gload16(gB + (size_t)16 * ldb + k0, lB1);
    __syncthreads();

    bf16x8 af[4], bfr[4];
#pragma unroll
    for (int mi = 0; mi < 4; ++mi)
      af[mi] = *(const bf16x8*)&As[(wm + mi * 16 + lm) * 32 + (lq << 3)];
#pragma unroll
    for (int ni = 0; ni < 4; ++ni)
      bfr[ni] = *(const bf16x8*)&Bs[(wn + ni * 16 + lm) * 32 + (lq << 3)];
#pragma unroll
    for (int mi = 0; mi < 4; ++mi)
#pragma unroll
      for (int ni = 0; ni < 4; ++ni)
        acc[mi][ni] = __builtin_amdgcn_mfma_f32_16x16x32_bf16(af[mi], bfr[ni], acc[mi][ni], 0, 0, 0);
  }

#pragma unroll
  for (int mi = 0; mi < 4; ++mi) {
    const int row = m0 + wm + mi * 16 + (lq << 2);
#pragma unroll
    for (int ni = 0; ni < 4; ++ni) {
      const int col = n0 + wn + ni * 16 + lm;
      if (col < N) {
#pragma unroll
        for (int r = 0; r < 4; ++r) {
          if constexpr (OMODE == 0)
            ((float*)Cv)[(size_t)(row + r) * ldc + col] = acc[mi][ni][r];
          else if constexpr (OMODE == 1)
            ((unsigned short*)Cv)[(size_t)(row + r) * ldc + col] = f2bf(acc[mi][ni][r]);
          else {
            const int rr2 = row + r;  // (B,NH,S,256): h=col>>8, d=col&255
            ((unsigned short*)Cv)[(((size_t)(rr2 >> 10) * NH_ + (col >> 8)) * S_ + (rr2 & 1023)) * 256 + (col & 255)] = f2bf(acc[mi][ni][r]);
          }
        }
      }
    }
  }
}

// ---------------------------------------------------------------------------
// LayerNorm: x fp32 rows (len L, stride xstride) -> y bf16 (stride ystride).
// ---------------------------------------------------------------------------
__global__ __launch_bounds__(256) void ln_kernel(
    const float* __restrict__ x, const float* __restrict__ g,
    const float* __restrict__ bias, unsigned short* __restrict__ y,
    const int L, const int xstride, const int ystride)
{
  __shared__ float sh[4];
  const int t = threadIdx.x;
  const float* xr = x + (size_t)blockIdx.x * xstride;
  unsigned short* yr = y + (size_t)blockIdx.x * ystride;
  const int n = L >> 8;
  float vals[6];
  float s = 0.f;
  for (int i = 0; i < n; ++i) { vals[i] = xr[t + (i << 8)]; s += vals[i]; }
#pragma unroll
  for (int off = 32; off; off >>= 1) s += __shfl_down(s, off);
  if ((t & 63) == 0) sh[t >> 6] = s;
  __syncthreads();
  const float mean = (sh[0] + sh[1] + sh[2] + sh[3]) / (float)L;
  float vs = 0.f;
  for (int i = 0; i < n; ++i) { const float d = vals[i] - mean; vs += d * d; }
#pragma unroll
  for (int off = 32; off; off >>= 1) vs += __shfl_down(vs, off);
  __syncthreads();
  if ((t & 63) == 0) sh[t >> 6] = vs;
  __syncthreads();
  const float inv = rsqrtf((sh[0] + sh[1] + sh[2] + sh[3]) / (float)L + EPS_);
  for (int i = 0; i < n; ++i) {
    const int c = t + (i << 8);
    yr[c] = f2bf((vals[i] - mean) * inv * g[c] + bias[c]);
  }
}

// ---------------------------------------------------------------------------
// RoPE on q_pe (cols 128..191 of each 192-wide head), in place on bf16 q.
// ---------------------------------------------------------------------------
__global__ __launch_bounds__(256) void rope_q_kernel(
    unsigned short* __restrict__ q, const float* __restrict__ cosp,
    const float* __restrict__ sinp, const int* __restrict__ pos)
{
  const int i = blockIdx.x * 256 + threadIdx.x;  // B*S*NH*32
  const int p = i & 31;
  const int h = (i >> 5) & 31;
  const int bs = i >> 10;
  const int pid = pos[bs];
  const size_t base = ((size_t)bs * NH_ + h) * QHD_ + 128;
  const float x1 = bf2f(q[base + p]);
  const float x2 = bf2f(q[base + p + 32]);
  const float* cr = cosp + (size_t)pid * 64;
  const float* sr = sinp + (size_t)pid * 64;
  q[base + p]      = f2bf(x1 * cr[p] - x2 * sr[p]);
  q[base + p + 32] = f2bf(x2 * cr[p + 32] + x1 * sr[p + 32]);
}

// RoPE on k_pe: ckv cols 512..575 (fp32) -> kpe bf16 (B,S,64)
__global__ __launch_bounds__(256) void rope_k_kernel(
    const float* __restrict__ ckv, const float* __restrict__ cosp,
    const float* __restrict__ sinp, const int* __restrict__ pos,
    unsigned short* __restrict__ kpe)
{
  const int i = blockIdx.x * 256 + threadIdx.x;  // B*S*32
  const int p = i & 31;
  const int bs = i >> 5;
  const int pid = pos[bs];
  const float* row = ckv + (size_t)bs * 576 + 512;
  const float x1 = row[p], x2 = row[p + 32];
  const float* cr = cosp + (size_t)pid * 64;
  const float* sr = sinp + (size_t)pid * 64;
  kpe[(size_t)bs * 64 + p]      = f2bf(x1 * cr[p] - x2 * sr[p]);
  kpe[(size_t)bs * 64 + p + 32] = f2bf(x2 * cr[p + 32] + x1 * sr[p + 32]);
}

// ---------------------------------------------------------------------------
// MFMA flash attention. Block = 4 waves = (b,h,64 q).
// Round-3 changes:
//  (a) prefetch state as TEN NAMED uint4 (no arrays, no address-of). Rounds
//      1-2 used uint4 arrays read back through a pointer cast -> SROA gave
//      up -> arrays demoted to scratch (WRITE_SIZE 230-338MB, scratch reads
//      between the barriers). Named vars + explicit .x/.y/.z/.w bit-ops keep
//      everything in VGPRs; the T14 async-STAGE finally works as designed.
//  (b) __launch_bounds__(256, 3): LDS caps occupancy at 3 blocks/CU anyway,
//      so allow up to ~170 VGPR.
//  (c) base-2 softmax (exp2), Vt XOR-swizzle (earlier rounds).
// ---------------------------------------------------------------------------
__global__ __launch_bounds__(256, 3) void attn_kernel(
    const unsigned short* __restrict__ qb, const unsigned short* __restrict__ kvb,
    const unsigned short* __restrict__ kpe, unsigned short* __restrict__ o)
{
  __shared__ unsigned short Ks[64 * 200];      // [k][d 0..191], stride 200
  __shared__ unsigned short Vt[128 * 72];      // [vd][k], stride 72, swizzled cols
  __shared__ unsigned short Ps[4 * 16 * 72];   // per-wave [m][k], stride 72

  const int t = threadIdx.x;
  const int qt = (int)gridDim.x - 1 - (int)blockIdx.x;  // longest first
  const int h = blockIdx.y, b = blockIdx.z;
  const int w = t >> 6, lane = t & 63;
  const int lm = lane & 15, lq = lane >> 4;
  const float SCALE2 = 0.10411754645f;  // 192^-0.5 * log2(e)

  const unsigned short* qp = qb + (((size_t)b * S_ + (qt << 6) + (w << 4) + lm) * NH_ + h) * QHD_;
  bf16x8 qf[6];
#pragma unroll
  for (int s = 0; s < 6; ++s) qf[s] = *(const bf16x8*)(qp + s * 32 + (lq << 3));

  const floatx4 vzero = {0.f, 0.f, 0.f, 0.f};
  floatx4 of[8];
#pragma unroll
  for (int i = 0; i < 8; ++i) of[i] = vzero;
  float mrow[4] = {-1e30f, -1e30f, -1e30f, -1e30f};
  float lrow[4] = {0.f, 0.f, 0.f, 0.f};

  const unsigned short* kvbase = kvb + (size_t)(b * NH_ + h) * S_ * 256;
  const unsigned short* kpbase = kpe + (size_t)b * S_ * 64;

  // ---- prefetch state: named registers only (no arrays -> no scratch) ----
  uint4 rKa0, rKa1, rKa2, rKa3;   // K-nope rows, 4 x (16 rows x 128 cols)/wave-pattern
  uint4 rKp0, rKp1;               // k_pe rows
  uint4 rVa0, rVb0, rVa1, rVb1;   // V row-pairs for transpose pack

  const int tK  = (t >> 4) * 256 + ((t & 15) << 3);   // K: row(t>>4), col(t&15)*8
  const int tKp = (t >> 3) * 64 + ((t & 7) << 3);     // kpe: row(t>>3), col(t&7)*8
  const int cg  = t & 15;                              // V: col-group
  const int tV  = ((t >> 4) << 1) * 256 + 128 + (cg << 3);

#define LOAD_TILE(KT) do { \
    const unsigned short* kvt_ = kvbase + (size_t)((KT) << 6) * 256; \
    const unsigned short* kpt_ = kpbase + (size_t)((KT) << 6) * 64;  \
    rKa0 = *(const uint4*)(kvt_ + tK);                                \
    rKa1 = *(const uint4*)(kvt_ + 16 * 256 + tK);                     \
    rKa2 = *(const uint4*)(kvt_ + 32 * 256 + tK);                     \
    rKa3 = *(const uint4*)(kvt_ + 48 * 256 + tK);                     \
    rKp0 = *(const uint4*)(kpt_ + tKp);                               \
    rKp1 = *(const uint4*)(kpt_ + 32 * 64 + tKp);                     \
    rVa0 = *(const uint4*)(kvt_ + tV);                                \
    rVb0 = *(const uint4*)(kvt_ + tV + 256);                          \
    rVa1 = *(const uint4*)(kvt_ + 32 * 256 + tV);                     \
    rVb1 = *(const uint4*)(kvt_ + 32 * 256 + tV + 256);               \
  } while (0)

  // V pack: rows kp*2, kp*2+1 -> Vt[vd][2kp], vd = cg*8+i, swizzled dword col
#define STORE_V(VA, VB, KP) do { \
    const int sc_ = ((KP) ^ ((cg & 7) << 2)) << 1;                      \
    unsigned short* vb_ = &Vt[(cg << 3) * 72 + sc_];                    \
    *(unsigned int*)(vb_ + 0 * 72) = ((VA).x & 0xffffu) | ((VB).x << 16);        \
    *(unsigned int*)(vb_ + 1 * 72) = ((VA).x >> 16)     | ((VB).x & 0xffff0000u);\
    *(unsigned int*)(vb_ + 2 * 72) = ((VA).y & 0xffffu) | ((VB).y << 16);        \
    *(unsigned int*)(vb_ + 3 * 72) = ((VA).y >> 16)     | ((VB).y & 0xffff0000u);\
    *(unsigned int*)(vb_ + 4 * 72) = ((VA).z & 0xffffu) | ((VB).z << 16);        \
    *(unsigned int*)(vb_ + 5 * 72) = ((VA).z >> 16)     | ((VB).z & 0xffff0000u);\
    *(unsigned int*)(vb_ + 6 * 72) = ((VA).w & 0xffffu) | ((VB).w << 16);        \
    *(unsigned int*)(vb_ + 7 * 72) = ((VA).w >> 16)     | ((VB).w & 0xffff0000u);\
  } while (0)

  LOAD_TILE(0);

  const int wKs  = (t >> 4) * 200 + ((t & 15) << 3);        // K dest
  const int wKps = (t >> 3) * 200 + 128 + ((t & 7) << 3);   // kpe dest

  for (int kt = 0; kt <= qt; ++kt) {
    __syncthreads();
    // ---- regs -> LDS (only LDS-write latency between the barriers) ----
    *(uint4*)&Ks[wKs]            = rKa0;
    *(uint4*)&Ks[16 * 200 + wKs] = rKa1;
    *(uint4*)&Ks[32 * 200 + wKs] = rKa2;
    *(uint4*)&Ks[48 * 200 + wKs] = rKa3;
    *(uint4*)&Ks[wKps]            = rKp0;
    *(uint4*)&Ks[32 * 200 + wKps] = rKp1;
    STORE_V(rVa0, rVb0, (t >> 4));
    STORE_V(rVa1, rVb1, 16 + (t >> 4));
    __syncthreads();
    // ---- issue next tile's global loads; they drain under compute ----
    if (kt < qt) LOAD_TILE(kt + 1);

    const bool diag = (kt == qt);
    const int nimax = diag ? w : 3;

    floatx4 sacc[4];
#pragma unroll
    for (int ni = 0; ni < 4; ++ni) sacc[ni] = vzero;
    for (int ni = 0; ni <= nimax; ++ni) {
#pragma unroll
      for (int s = 0; s < 6; ++s) {
        const bf16x8 kf = *(const bf16x8*)&Ks[(ni * 16 + lm) * 200 + s * 32 + (lq << 3)];
        sacc[ni] = __builtin_amdgcn_mfma_f32_16x16x32_bf16(qf[s], kf, sacc[ni], 0, 0, 0);
      }
    }

#pragma unroll
    for (int r = 0; r < 4; ++r) {
      const int rq = (lq << 2) + r;
      float sc[4], mx = -1e30f;
#pragma unroll
      for (int ni = 0; ni < 4; ++ni) {
        float v = sacc[ni][r] * SCALE2;   // base-2 domain
        if (ni > nimax) v = -1e30f;
        if (diag && ni == w && lm > rq) v = -1e30f;
        sc[ni] = v;
        mx = fmaxf(mx, v);
      }
#pragma unroll
      for (int off = 8; off; off >>= 1) mx = fmaxf(mx, __shfl_xor(mx, off));
      const float mnew = fmaxf(mrow[r], mx);
      const float al = __builtin_amdgcn_exp2f(mrow[r] - mnew);
      mrow[r] = mnew;
      float ps = 0.f;
#pragma unroll
      for (int ni = 0; ni < 4; ++ni) {
        const float p = __builtin_amdgcn_exp2f(sc[ni] - mnew);
        ps += p;
        Ps[(w * 16 + rq) * 72 + ni * 16 + lm] = f2bf(p);
      }
#pragma unroll
      for (int off = 8; off; off >>= 1) ps += __shfl_xor(ps, off);
      lrow[r] = lrow[r] * al + ps;
#pragma unroll
      for (int vt = 0; vt < 8; ++vt) of[vt][r] *= al;
    }

    const int ksmax = diag ? ((w >= 2) ? 1 : 0) : 1;
    for (int ks2 = 0; ks2 <= ksmax; ++ks2) {
      const bf16x8 pf = *(const bf16x8*)&Ps[(w * 16 + lm) * 72 + ks2 * 32 + (lq << 3)];
#pragma unroll
      for (int vt = 0; vt < 8; ++vt) {
        const int rr = vt * 16 + lm;
        const int c0 = (ks2 << 4) + (lq << 2);  // dword col
        const bf16x8 vf = *(const bf16x8*)&Vt[rr * 72 + ((c0 ^ (((rr >> 3) & 7) << 2)) << 1)];
        of[vt] = __builtin_amdgcn_mfma_f32_16x16x32_bf16(pf, vf, of[vt], 0, 0, 0);
      }
    }
  }

#pragma unroll
  for (int r = 0; r < 4; ++r) {
    const int qrow = (qt << 6) + (w << 4) + (lq << 2) + r;
    const float inv = 1.f / lrow[r];
    unsigned short* orow = o + ((size_t)b * S_ + qrow) * 4096 + h * 128;
#pragma unroll
    for (int vt = 0; vt < 8; ++vt)
      orow[vt * 16 + lm] = f2bf(of[vt][r] * inv);
  }
#undef LOAD_TILE
#undef STORE_V
}

// ---------------------------------------------------------------------------
extern "C" void kernel_launch(void* const* d_in, const int* in_sizes, int n_in,
                              void* d_out, int out_size, void* d_ws, size_t ws_size,
                              hipStream_t stream) {
  (void)in_sizes; (void)n_in; (void)out_size; (void)ws_size;
  const float* hs   = (const float*)d_in[0];
  const float* cosp = (const float*)d_in[1];
  const float* sinp = (const float*)d_in[2];
  const int*   pos  = (const int*)d_in[3];
  const float* Wqa  = (const float*)d_in[4];
  const float* gqa  = (const float*)d_in[5];
  const float* bqa  = (const float*)d_in[6];
  const float* Wqb  = (const float*)d_in[7];
  const float* Wkva = (const float*)d_in[8];
  const float* gkva = (const float*)d_in[9];
  const float* bkva = (const float*)d_in[10];
  const float* Wkvb = (const float*)d_in[11];
  const float* Wo   = (const float*)d_in[12];
  float* out = (float*)d_out;

  char* ws = (char*)d_ws;
  // lifetime-aliased workspace (~204.5 MiB total)
  unsigned short* hsb   = (unsigned short*)(ws);               // 33,554,432
  float*          q_a   = (float*)(ws + 33554432);             // 25,165,824
  unsigned short* qb    = (unsigned short*)(ws);               // alias over hsb+q_a (50,331,648 <= 58,720,256)
  unsigned short* WqaT  = (unsigned short*)(ws + 58720256);    // 12,582,912 (1536x4096)
  unsigned short* WkvaT = (unsigned short*)(ws + 71303168);    //  5,242,880 (640x4096, rows 576+ poison)
  unsigned short* qln   = (unsigned short*)(ws + 58720256);    // alias over WqaT (12,582,912)
  unsigned short* kvln  = (unsigned short*)(ws + 71303168);    // alias over WkvaT (4,194,304)
  unsigned short* WqbT  = (unsigned short*)(ws + 76546048);    // 18,874,368 (6144x1536)
  float*          ckv   = (float*)(ws + 95420416);             //  9,437,184
  unsigned short* WkvbT = (unsigned short*)(ws + 104857600);   //  8,388,608 (8192x512)
  unsigned short* ob    = (unsigned short*)(ws + 76546048);    // alias over WqbT+ckv+WkvbT (33,554,432 <= 36,700,160)
  unsigned short* WoT   = (unsigned short*)(ws + 113246208);   // 33,554,432 (4096x4096)
  unsigned short* kvb   = (unsigned short*)(ws + 146800640);   // 67,108,864 (B,NH,S,256)
  unsigned short* kpe   = (unsigned short*)(ws + 213909504);   //    524,288

  const dim3 blk(256);
  // prepass: bf16 convert + weight transposes
  convert_kernel<<<dim3(8192), blk, 0, stream>>>(hs, hsb);
  transpose_kernel<<<dim3(48, 128), blk, 0, stream>>>(Wqa, WqaT, 4096, 1536);
  transpose_kernel<<<dim3(18, 128), blk, 0, stream>>>(Wkva, WkvaT, 4096, 576);
  transpose_kernel<<<dim3(192, 48), blk, 0, stream>>>(Wqb, WqbT, 1536, 6144);
  transpose_kernel<<<dim3(256, 16), blk, 0, stream>>>(Wkvb, WkvbT, 512, 8192);
  transpose_kernel<<<dim3(128, 128), blk, 0, stream>>>(Wo, WoT, 4096, 4096);

  // q_a = hs @ Wqa ; ckv = hs @ Wkva
  gemm_bt<0><<<dim3(32, 12), blk, 0, stream>>>(hsb, WqaT, q_a, 1536, 4096, 4096, 4096, 1536);
  gemm_bt<0><<<dim3(32, 5), blk, 0, stream>>>(hsb, WkvaT, ckv, 576, 4096, 4096, 4096, 576);
  // LN -> bf16 (qln over WqaT, kvln over WkvaT — both weights dead now)
  ln_kernel<<<dim3(4096), blk, 0, stream>>>(q_a, gqa, bqa, qln, 1536, 1536, 1536);
  ln_kernel<<<dim3(4096), blk, 0, stream>>>(ckv, gkva, bkva, kvln, 512, 576, 512);
  rope_k_kernel<<<dim3(512), blk, 0, stream>>>(ckv, cosp, sinp, pos, kpe);
  // qb = qln @ Wqb (qb over hsb+q_a — both dead now)
  gemm_bt<1><<<dim3(32, 48), blk, 0, stream>>>(qln, WqbT, qb, 6144, 1536, 1536, 1536, 6144);
  rope_q_kernel<<<dim3(16384), blk, 0, stream>>>(qb, cosp, sinp, pos);
  // kvb = kvln @ Wkvb, scattered to (B,NH,S,256)
  gemm_bt<2><<<dim3(32, 64), blk, 0, stream>>>(kvln, WkvbT, kvb, 8192, 512, 512, 512, 8192);
  // attention (ob over WqbT+ckv+WkvbT — all dead now)
  attn_kernel<<<dim3(16, 32, 4), blk, 0, stream>>>(qb, kvb, kpe, ob);
  // out = ob @ Wo
  gemm_bt<0><<<dim3(32, 32), blk, 0, stream>>>(ob, WoT, out, 4096, 4096, 4096, 4096, 4096);
}

// Round 4
// 983.265 us; speedup vs baseline: 1.1638x; 1.0001x over previous
//
#include <hip/hip_runtime.h>

// MLA shapes (fixed)
#define B_ 4
#define S_ 1024
#define H_ 4096
#define NH_ 32
#define QHD_ 192
#define EPS_ 1e-6f

typedef __bf16 bf16x8 __attribute__((ext_vector_type(8)));
typedef float floatx4 __attribute__((ext_vector_type(4)));

__device__ __forceinline__ unsigned short f2bf(float f) {
  unsigned int u = __builtin_bit_cast(unsigned int, f);
  u += 0x7fffu + ((u >> 16) & 1u);   // round-to-nearest-even (finite data only)
  return (unsigned short)(u >> 16);
}
__device__ __forceinline__ float bf2f(unsigned short s) {
  return __builtin_bit_cast(float, ((unsigned int)s) << 16);
}

// async global->LDS, 16B per lane; LDS dest = wave-uniform base + lane*16 (m104)
__device__ __forceinline__ void gload16(const unsigned short* g, unsigned short* l) {
  __builtin_amdgcn_global_load_lds(
      (const __attribute__((address_space(1))) void*)g,
      (__attribute__((address_space(3))) void*)l, 16, 0, 0);
}

// ---------------------------------------------------------------------------
// fp32 -> bf16 convert (hs), 8 elems/thread
// ---------------------------------------------------------------------------
__global__ __launch_bounds__(256) void convert_kernel(
    const float* __restrict__ x, unsigned short* __restrict__ y)
{
  const int i = (blockIdx.x * 256 + threadIdx.x) * 8;
  const float4 a = *(const float4*)(x + i);
  const float4 b = *(const float4*)(x + i + 4);
  ushort4 u, v;
  u.x = f2bf(a.x); u.y = f2bf(a.y); u.z = f2bf(a.z); u.w = f2bf(a.w);
  v.x = f2bf(b.x); v.y = f2bf(b.y); v.z = f2bf(b.z); v.w = f2bf(b.w);
  *(ushort4*)(y + i) = u;
  *(ushort4*)(y + i + 4) = v;
}

// ---------------------------------------------------------------------------
// W (KxN fp32 row-major) -> Wt (NxK bf16 row-major). 32x32 LDS tiles.
// ---------------------------------------------------------------------------
__global__ __launch_bounds__(256) void transpose_kernel(
    const float* __restrict__ W, unsigned short* __restrict__ Wt,
    const int K, const int N)
{
  __shared__ float tile[32][33];
  const int tx = threadIdx.x & 31, ty = threadIdx.x >> 5;
  const int nb = blockIdx.x << 5, kb = blockIdx.y << 5;
#pragma unroll
  for (int j = 0; j < 4; ++j)
    tile[ty + j * 8][tx] = W[(size_t)(kb + ty + j * 8) * N + nb + tx];
  __syncthreads();
#pragma unroll
  for (int j = 0; j < 4; ++j)
    Wt[(size_t)(nb + ty + j * 8) * K + kb + tx] = f2bf(tile[tx][ty + j * 8]);
}

// ---------------------------------------------------------------------------
// m97-class GEMM: C(MxN) = A(MxK) @ Bt(NxK)^T, both bf16, staged via
// global_load_lds width=16 into unpadded LDS [128][32]. 128x128 tile, BK=32,
// 4 waves (2x2 of 64x64), mfma_f32_16x16x32_bf16.
// OMODE: 0 = fp32 row-major, 1 = bf16 row-major, 2 = bf16 (B,NH,S,256) kv.
// M%128==0, K%32==0; Bt rows padded to 128-mult (pad contents finite poison).
// ---------------------------------------------------------------------------
template<int OMODE>
__global__ __launch_bounds__(256, 2) void gemm_bt(
    const unsigned short* __restrict__ A, const unsigned short* __restrict__ Bt,
    void* __restrict__ Cv, const int N, const int K,
    const int lda, const int ldb, const int ldc)
{
  __shared__ unsigned short As[128 * 32];
  __shared__ unsigned short Bs[128 * 32];

  const int t = threadIdx.x;
  const int m0 = blockIdx.x * 128, n0 = blockIdx.y * 128;
  const int w = t >> 6, lane = t & 63;
  const int wm = (w >> 1) << 6, wn = (w & 1) << 6;
  const int lm = lane & 15, lq = lane >> 4;

  const floatx4 vzero = {0.f, 0.f, 0.f, 0.f};
  floatx4 acc[4][4];
#pragma unroll
  for (int i = 0; i < 4; ++i)
#pragma unroll
    for (int j = 0; j < 4; ++j) acc[i][j] = vzero;

  // staging: wave w does calls i=0,1; call covers 16 rows x 32 cols (1 KB).
  // lane -> row (w*32 + i*16 + lane/4), chunk kc = lane&3 (8 shorts).
  const int srow = (w << 5) + (lane >> 2);
  const int skc = (lane & 3) << 3;
  const unsigned short* gA = A + (size_t)(m0 + srow) * lda + skc;
  const unsigned short* gB = Bt + (size_t)(n0 + srow) * ldb + skc;
  unsigned short* lA0 = &As[(w << 1) * 512];
  unsigned short* lA1 = &As[((w << 1) + 1) * 512];
  unsigned short* lB0 = &Bs[(w << 1) * 512];
  unsigned short* lB1 = &Bs[((w << 1) + 1) * 512];

  const int nk = K >> 5;
  for (int kb = 0; kb < nk; ++kb) {
    const int k0 = kb << 5;
    __syncthreads();
    gload16(gA + k0, lA0);
    gload16(gA + (size_t)16 * lda + k0, lA1);
    gload16(gB + k0, lB0);
    gload16(gB + (size_t)16 * ldb + k0, lB1);
    __syncthreads();

    bf16x8 af[4], bfr[4];
#pragma unroll
    for (int mi = 0; mi < 4; ++mi)
      af[mi] = *(const bf16x8*)&As[(wm + mi * 16 + lm) * 32 + (lq << 3)];
#pragma unroll
    for (int ni = 0; ni < 4; ++ni)
      bfr[ni] = *(const bf16x8*)&Bs[(wn + ni * 16 + lm) * 32 + (lq << 3)];
#pragma unroll
    for (int mi = 0; mi < 4; ++mi)
#pragma unroll
      for (int ni = 0; ni < 4; ++ni)
        acc[mi][ni] = __builtin_amdgcn_mfma_f32_16x16x32_bf16(af[mi], bfr[ni], acc[mi][ni], 0, 0, 0);
  }

#pragma unroll
  for (int mi = 0; mi < 4; ++mi) {
    const int row = m0 + wm + mi * 16 + (lq << 2);
#pragma unroll
    for (int ni = 0; ni < 4; ++ni) {
      const int col = n0 + wn + ni * 16 + lm;
      if (col < N) {
#pragma unroll
        for (int r = 0; r < 4; ++r) {
          if constexpr (OMODE == 0)
            ((float*)Cv)[(size_t)(row + r) * ldc + col] = acc[mi][ni][r];
          else if constexpr (OMODE == 1)
            ((unsigned short*)Cv)[(size_t)(row + r) * ldc + col] = f2bf(acc[mi][ni][r]);
          else {
            const int rr2 = row + r;  // (B,NH,S,256): h=col>>8, d=col&255
            ((unsigned short*)Cv)[(((size_t)(rr2 >> 10) * NH_ + (col >> 8)) * S_ + (rr2 & 1023)) * 256 + (col & 255)] = f2bf(acc[mi][ni][r]);
          }
        }
      }
    }
  }
}

// ---------------------------------------------------------------------------
// LayerNorm: x fp32 rows (len L, stride xstride) -> y bf16 (stride ystride).
// ---------------------------------------------------------------------------
__global__ __launch_bounds__(256) void ln_kernel(
    const float* __restrict__ x, const float* __restrict__ g,
    const float* __restrict__ bias, unsigned short* __restrict__ y,
    const int L, const int xstride, const int ystride)
{
  __shared__ float sh[4];
  const int t = threadIdx.x;
  const float* xr = x + (size_t)blockIdx.x * xstride;
  unsigned short* yr = y + (size_t)blockIdx.x * ystride;
  const int n = L >> 8;
  float vals[6];
  float s = 0.f;
  for (int i = 0; i < n; ++i) { vals[i] = xr[t + (i << 8)]; s += vals[i]; }
#pragma unroll
  for (int off = 32; off; off >>= 1) s += __shfl_down(s, off);
  if ((t & 63) == 0) sh[t >> 6] = s;
  __syncthreads();
  const float mean = (sh[0] + sh[1] + sh[2] + sh[3]) / (float)L;
  float vs = 0.f;
  for (int i = 0; i < n; ++i) { const float d = vals[i] - mean; vs += d * d; }
#pragma unroll
  for (int off = 32; off; off >>= 1) vs += __shfl_down(vs, off);
  __syncthreads();
  if ((t & 63) == 0) sh[t >> 6] = vs;
  __syncthreads();
  const float inv = rsqrtf((sh[0] + sh[1] + sh[2] + sh[3]) / (float)L + EPS_);
  for (int i = 0; i < n; ++i) {
    const int c = t + (i << 8);
    yr[c] = f2bf((vals[i] - mean) * inv * g[c] + bias[c]);
  }
}

// ---------------------------------------------------------------------------
// RoPE on q_pe (cols 128..191 of each 192-wide head), in place on bf16 q.
// ---------------------------------------------------------------------------
__global__ __launch_bounds__(256) void rope_q_kernel(
    unsigned short* __restrict__ q, const float* __restrict__ cosp,
    const float* __restrict__ sinp, const int* __restrict__ pos)
{
  const int i = blockIdx.x * 256 + threadIdx.x;  // B*S*NH*32
  const int p = i & 31;
  const int h = (i >> 5) & 31;
  const int bs = i >> 10;
  const int pid = pos[bs];
  const size_t base = ((size_t)bs * NH_ + h) * QHD_ + 128;
  const float x1 = bf2f(q[base + p]);
  const float x2 = bf2f(q[base + p + 32]);
  const float* cr = cosp + (size_t)pid * 64;
  const float* sr = sinp + (size_t)pid * 64;
  q[base + p]      = f2bf(x1 * cr[p] - x2 * sr[p]);
  q[base + p + 32] = f2bf(x2 * cr[p + 32] + x1 * sr[p + 32]);
}

// RoPE on k_pe: ckv cols 512..575 (fp32) -> kpe bf16 (B,S,64)
__global__ __launch_bounds__(256) void rope_k_kernel(
    const float* __restrict__ ckv, const float* __restrict__ cosp,
    const float* __restrict__ sinp, const int* __restrict__ pos,
    unsigned short* __restrict__ kpe)
{
  const int i = blockIdx.x * 256 + threadIdx.x;  // B*S*32
  const int p = i & 31;
  const int bs = i >> 5;
  const int pid = pos[bs];
  const float* row = ckv + (size_t)bs * 576 + 512;
  const float x1 = row[p], x2 = row[p + 32];
  const float* cr = cosp + (size_t)pid * 64;
  const float* sr = sinp + (size_t)pid * 64;
  kpe[(size_t)bs * 64 + p]      = f2bf(x1 * cr[p] - x2 * sr[p]);
  kpe[(size_t)bs * 64 + p + 32] = f2bf(x2 * cr[p + 32] + x1 * sr[p + 32]);
}

// ---------------------------------------------------------------------------
// MFMA flash attention. Block = 8 waves = (b,h,128 q). Round-4 changes:
//  (a) 512-thread blocks, 128 q-rows: staging per tile is constant, so
//      doubling q-rows halves total tile-stagings (136->72 per (b,h)) and
//      halves KV global traffic. LDS 62464B -> 2 blocks/CU = 16 waves/CU
//      (was 12). Prefetch shrinks to 5 named uint4/thread (20 VGPR).
//  (b) static-index compute: named floatx4 sacc0..3 + wave-uniform
//      if(nimax>=k) guards, PV ks2 unrolled with rel>=32 guard. Kills the
//      runtime-indexed sacc[] alloca (the last ~38MB of scratch traffic).
//  (c) causal geometry per wave: rel = (q0*128+w*16) - kt*64.
//      rel>=64 full; 0<=rel<64 diag (nimax=rel>>4, mask lm>rq at ni==nimax);
//      rel<0 wave skips compute (barriers+staging only; last tile, waves 0-3).
//  (d) carried: T14 named-reg prefetch, Vt XOR-swizzle, base-2 softmax.
// ---------------------------------------------------------------------------
__global__ __launch_bounds__(512, 4) void attn_kernel(
    const unsigned short* __restrict__ qb, const unsigned short* __restrict__ kvb,
    const unsigned short* __restrict__ kpe, unsigned short* __restrict__ o)
{
  __shared__ unsigned short Ks[64 * 200];      // [k][d 0..191], stride 200
  __shared__ unsigned short Vt[128 * 72];      // [vd][k], stride 72, swizzled cols
  __shared__ unsigned short Ps[8 * 16 * 72];   // per-wave [m][k], stride 72

  const int t = threadIdx.x;
  const int q0 = (int)gridDim.x - 1 - (int)blockIdx.x;  // longest first
  const int h = blockIdx.y, b = blockIdx.z;
  const int w = t >> 6, lane = t & 63;
  const int lm = lane & 15, lq = lane >> 4;
  const float SCALE2 = 0.10411754645f;  // 192^-0.5 * log2(e)

  const unsigned short* qp = qb + (((size_t)b * S_ + (q0 << 7) + (w << 4) + lm) * NH_ + h) * QHD_;
  bf16x8 qf[6];
#pragma unroll
  for (int s = 0; s < 6; ++s) qf[s] = *(const bf16x8*)(qp + s * 32 + (lq << 3));

  const floatx4 vzero = {0.f, 0.f, 0.f, 0.f};
  floatx4 of[8];
#pragma unroll
  for (int i = 0; i < 8; ++i) of[i] = vzero;
  float mrow[4] = {-1e30f, -1e30f, -1e30f, -1e30f};
  float lrow[4] = {0.f, 0.f, 0.f, 0.f};

  const unsigned short* kvbase = kvb + (size_t)(b * NH_ + h) * S_ * 256;
  const unsigned short* kpbase = kpe + (size_t)b * S_ * 64;

  // ---- prefetch state: 5 named uint4 (no arrays -> no scratch) ----
  uint4 rKa0, rKa1, rKp0, rVa0, rVb0;

  const int tK  = (t >> 4) * 256 + ((t & 15) << 3);   // K rows 0..31, chunk t&15
  const int tKp = (t >> 3) * 64 + ((t & 7) << 3);     // kpe rows 0..63
  const int cg  = t & 15;                              // V col-group
  const int kp  = t >> 4;                              // V row-pair 0..31
  const int tV  = (kp << 1) * 256 + 128 + (cg << 3);

#define LOAD_TILE(KT) do { \
    const unsigned short* kvt_ = kvbase + (size_t)((KT) << 6) * 256; \
    const unsigned short* kpt_ = kpbase + (size_t)((KT) << 6) * 64;  \
    rKa0 = *(const uint4*)(kvt_ + tK);                                \
    rKa1 = *(const uint4*)(kvt_ + 32 * 256 + tK);                     \
    rKp0 = *(const uint4*)(kpt_ + tKp);                               \
    rVa0 = *(const uint4*)(kvt_ + tV);                                \
    rVb0 = *(const uint4*)(kvt_ + tV + 256);                          \
  } while (0)

  LOAD_TILE(0);

  const int wKs  = (t >> 4) * 200 + ((t & 15) << 3);        // K dest rows 0..31
  const int wKps = (t >> 3) * 200 + 128 + ((t & 7) << 3);   // kpe dest
  const int scv  = (kp ^ ((cg & 7) << 2)) << 1;             // swizzled V col
  unsigned short* vbp = &Vt[(cg << 3) * 72 + scv];

  const int ktmax = (q0 << 1) + 1;
  const int qrel0 = (q0 << 7) + (w << 4);   // wave's first q-row

  for (int kt = 0; kt <= ktmax; ++kt) {
    __syncthreads();
    // ---- regs -> LDS (only LDS-write latency between the barriers) ----
    *(uint4*)&Ks[wKs]            = rKa0;
    *(uint4*)&Ks[32 * 200 + wKs] = rKa1;
    *(uint4*)&Ks[wKps]           = rKp0;
    *(unsigned int*)(vbp + 0 * 72) = (rVa0.x & 0xffffu) | (rVb0.x << 16);
    *(unsigned int*)(vbp + 1 * 72) = (rVa0.x >> 16)     | (rVb0.x & 0xffff0000u);
    *(unsigned int*)(vbp + 2 * 72) = (rVa0.y & 0xffffu) | (rVb0.y << 16);
    *(unsigned int*)(vbp + 3 * 72) = (rVa0.y >> 16)     | (rVb0.y & 0xffff0000u);
    *(unsigned int*)(vbp + 4 * 72) = (rVa0.z & 0xffffu) | (rVb0.z << 16);
    *(unsigned int*)(vbp + 5 * 72) = (rVa0.z >> 16)     | (rVb0.z & 0xffff0000u);
    *(unsigned int*)(vbp + 6 * 72) = (rVa0.w & 0xffffu) | (rVb0.w << 16);
    *(unsigned int*)(vbp + 7 * 72) = (rVa0.w >> 16)     | (rVb0.w & 0xffff0000u);
    __syncthreads();
    // ---- issue next tile's global loads; they drain under compute ----
    if (kt < ktmax) LOAD_TILE(kt + 1);

    const int rel = qrel0 - (kt << 6);   // wave-uniform
    if (rel >= 0) {
      const int nimax = (rel >= 64) ? 3 : (rel >> 4);

      floatx4 s0v = vzero, s1v = vzero, s2v = vzero, s3v = vzero;
#define QKNI(SACC, NI) do { \
      _Pragma("unroll") \
      for (int s = 0; s < 6; ++s) { \
        const bf16x8 kf = *(const bf16x8*)&Ks[((NI) * 16 + lm) * 200 + s * 32 + (lq << 3)]; \
        SACC = __builtin_amdgcn_mfma_f32_16x16x32_bf16(qf[s], kf, SACC, 0, 0, 0); \
      } } while (0)
      QKNI(s0v, 0);
      if (nimax >= 1) QKNI(s1v, 1);
      if (nimax >= 2) QKNI(s2v, 2);
      if (nimax >= 3) QKNI(s3v, 3);
#undef QKNI

      const bool dg = (rel < 64);
#pragma unroll
      for (int r = 0; r < 4; ++r) {
        const int rq = (lq << 2) + r;
        float a0 = s0v[r] * SCALE2;
        float a1 = s1v[r] * SCALE2;
        float a2 = s2v[r] * SCALE2;
        float a3 = s3v[r] * SCALE2;
        if (nimax < 1) a1 = -1e30f;
        if (nimax < 2) a2 = -1e30f;
        if (nimax < 3) a3 = -1e30f;
        if (dg) {
          const bool m = lm > rq;
          if (nimax == 0 && m) a0 = -1e30f;
          if (nimax == 1 && m) a1 = -1e30f;
          if (nimax == 2 && m) a2 = -1e30f;
          if (nimax == 3 && m) a3 = -1e30f;
        }
        float mx = fmaxf(fmaxf(a0, a1), fmaxf(a2, a3));
#pragma unroll
        for (int off = 8; off; off >>= 1) mx = fmaxf(mx, __shfl_xor(mx, off));
        const float mnew = fmaxf(mrow[r], mx);
        const float al = __builtin_amdgcn_exp2f(mrow[r] - mnew);
        mrow[r] = mnew;
        const float p0 = __builtin_amdgcn_exp2f(a0 - mnew);
        const float p1 = __builtin_amdgcn_exp2f(a1 - mnew);
        const float p2 = __builtin_amdgcn_exp2f(a2 - mnew);
        const float p3 = __builtin_amdgcn_exp2f(a3 - mnew);
        unsigned short* pr = &Ps[(w * 16 + rq) * 72 + lm];
        pr[0]  = f2bf(p0);
        pr[16] = f2bf(p1);
        pr[32] = f2bf(p2);
        pr[48] = f2bf(p3);
        float ps = (p0 + p1) + (p2 + p3);
#pragma unroll
        for (int off = 8; off; off >>= 1) ps += __shfl_xor(ps, off);
        lrow[r] = lrow[r] * al + ps;
#pragma unroll
        for (int vt = 0; vt < 8; ++vt) of[vt][r] *= al;
      }

      // PV: ks2 = 0 always; ks2 = 1 iff rel >= 32
      {
        const bf16x8 pf = *(const bf16x8*)&Ps[(w * 16 + lm) * 72 + (lq << 3)];
#pragma unroll
        for (int vt = 0; vt < 8; ++vt) {
          const int rr = vt * 16 + lm;
          const int c0 = (lq << 2);
          const bf16x8 vf = *(const bf16x8*)&Vt[rr * 72 + ((c0 ^ (((rr >> 3) & 7) << 2)) << 1)];
          of[vt] = __builtin_amdgcn_mfma_f32_16x16x32_bf16(pf, vf, of[vt], 0, 0, 0);
        }
      }
      if (rel >= 32) {
        const bf16x8 pf = *(const bf16x8*)&Ps[(w * 16 + lm) * 72 + 32 + (lq << 3)];
#pragma unroll
        for (int vt = 0; vt < 8; ++vt) {
          const int rr = vt * 16 + lm;
          const int c0 = 16 + (lq << 2);
          const bf16x8 vf = *(const bf16x8*)&Vt[rr * 72 + ((c0 ^ (((rr >> 3) & 7) << 2)) << 1)];
          of[vt] = __builtin_amdgcn_mfma_f32_16x16x32_bf16(pf, vf, of[vt], 0, 0, 0);
        }
      }
    }
  }

#pragma unroll
  for (int r = 0; r < 4; ++r) {
    const int qrow = (q0 << 7) + (w << 4) + (lq << 2) + r;
    const float inv = 1.f / lrow[r];
    unsigned short* orow = o + ((size_t)b * S_ + qrow) * 4096 + h * 128;
#pragma unroll
    for (int vt = 0; vt < 8; ++vt)
      orow[vt * 16 + lm] = f2bf(of[vt][r] * inv);
  }
#undef LOAD_TILE
}

// ---------------------------------------------------------------------------
extern "C" void kernel_launch(void* const* d_in, const int* in_sizes, int n_in,
                              void* d_out, int out_size, void* d_ws, size_t ws_size,
                              hipStream_t stream) {
  (void)in_sizes; (void)n_in; (void)out_size; (void)ws_size;
  const float* hs   = (const float*)d_in[0];
  const float* cosp = (const float*)d_in[1];
  const float* sinp = (const float*)d_in[2];
  const int*   pos  = (const int*)d_in[3];
  const float* Wqa  = (const float*)d_in[4];
  const float* gqa  = (const float*)d_in[5];
  const float* bqa  = (const float*)d_in[6];
  const float* Wqb  = (const float*)d_in[7];
  const float* Wkva = (const float*)d_in[8];
  const float* gkva = (const float*)d_in[9];
  const float* bkva = (const float*)d_in[10];
  const float* Wkvb = (const float*)d_in[11];
  const float* Wo   = (const float*)d_in[12];
  float* out = (float*)d_out;

  char* ws = (char*)d_ws;
  // lifetime-aliased workspace (~204.5 MiB total)
  unsigned short* hsb   = (unsigned short*)(ws);               // 33,554,432
  float*          q_a   = (float*)(ws + 33554432);             // 25,165,824
  unsigned short* qb    = (unsigned short*)(ws);               // alias over hsb+q_a (50,331,648 <= 58,720,256)
  unsigned short* WqaT  = (unsigned short*)(ws + 58720256);    // 12,582,912 (1536x4096)
  unsigned short* WkvaT = (unsigned short*)(ws + 71303168);    //  5,242,880 (640x4096, rows 576+ poison)
  unsigned short* qln   = (unsigned short*)(ws + 58720256);    // alias over WqaT (12,582,912)
  unsigned short* kvln  = (unsigned short*)(ws + 71303168);    // alias over WkvaT (4,194,304)
  unsigned short* WqbT  = (unsigned short*)(ws + 76546048);    // 18,874,368 (6144x1536)
  float*          ckv   = (float*)(ws + 95420416);             //  9,437,184
  unsigned short* WkvbT = (unsigned short*)(ws + 104857600);   //  8,388,608 (8192x512)
  unsigned short* ob    = (unsigned short*)(ws + 76546048);    // alias over WqbT+ckv+WkvbT (33,554,432 <= 36,700,160)
  unsigned short* WoT   = (unsigned short*)(ws + 113246208);   // 33,554,432 (4096x4096)
  unsigned short* kvb   = (unsigned short*)(ws + 146800640);   // 67,108,864 (B,NH,S,256)
  unsigned short* kpe   = (unsigned short*)(ws + 213909504);   //    524,288

  const dim3 blk(256);
  // prepass: bf16 convert + weight transposes
  convert_kernel<<<dim3(8192), blk, 0, stream>>>(hs, hsb);
  transpose_kernel<<<dim3(48, 128), blk, 0, stream>>>(Wqa, WqaT, 4096, 1536);
  transpose_kernel<<<dim3(18, 128), blk, 0, stream>>>(Wkva, WkvaT, 4096, 576);
  transpose_kernel<<<dim3(192, 48), blk, 0, stream>>>(Wqb, WqbT, 1536, 6144);
  transpose_kernel<<<dim3(256, 16), blk, 0, stream>>>(Wkvb, WkvbT, 512, 8192);
  transpose_kernel<<<dim3(128, 128), blk, 0, stream>>>(Wo, WoT, 4096, 4096);

  // q_a = hs @ Wqa ; ckv = hs @ Wkva
  gemm_bt<0><<<dim3(32, 12), blk, 0, stream>>>(hsb, WqaT, q_a, 1536, 4096, 4096, 4096, 1536);
  gemm_bt<0><<<dim3(32, 5), blk, 0, stream>>>(hsb, WkvaT, ckv, 576, 4096, 4096, 4096, 576);
  // LN -> bf16 (qln over WqaT, kvln over WkvaT — both weights dead now)
  ln_kernel<<<dim3(4096), blk, 0, stream>>>(q_a, gqa, bqa, qln, 1536, 1536, 1536);
  ln_kernel<<<dim3(4096), blk, 0, stream>>>(ckv, gkva, bkva, kvln, 512, 576, 512);
  rope_k_kernel<<<dim3(512), blk, 0, stream>>>(ckv, cosp, sinp, pos, kpe);
  // qb = qln @ Wqb (qb over hsb+q_a — both dead now)
  gemm_bt<1><<<dim3(32, 48), blk, 0, stream>>>(qln, WqbT, qb, 6144, 1536, 1536, 1536, 6144);
  rope_q_kernel<<<dim3(16384), blk, 0, stream>>>(qb, cosp, sinp, pos);
  // kvb = kvln @ Wkvb, scattered to (B,NH,S,256)
  gemm_bt<2><<<dim3(32, 64), blk, 0, stream>>>(kvln, WkvbT, kvb, 8192, 512, 512, 512, 8192);
  // attention (ob over WqbT+ckv+WkvbT — all dead now)
  attn_kernel<<<dim3(8, 32, 4), dim3(512), 0, stream>>>(qb, kvb, kpe, ob);
  // out = ob @ Wo
  gemm_bt<0><<<dim3(32, 32), blk, 0, stream>>>(ob, WoT, out, 4096, 4096, 4096, 4096, 4096);
}